// Round 1
// baseline (1676.917 us; speedup 1.0000x reference)
//
#include <hip/hip_runtime.h>
#include <hip/hip_bf16.h>

#define SIZE_D 512
#define HEADS  8
#define HDIM   64
#define BATCH  32
#define SEQ    512
#define SCALE  0.125f   // 1/sqrt(64)
#define NROWS  (BATCH * SEQ)   // 16384

// ---------------------------------------------------------------------------
// GEMM: C[m,n] = dot(A[m,:], W[n,:]) + bias[n]        (i.e. A @ W^T + b)
// RELU_RES=1: C[m,n] = R[m,n] + relu(z)
// A: [M,512] row-major, W: [512,512] row-major. M = 16384, N = 512.
// tiles: BM=BN=64, BK=32, 256 threads, 4x4 micro-tile per thread.
// ---------------------------------------------------------------------------
template <int RELU_RES>
__global__ __launch_bounds__(256) void gemm_bias(const float* __restrict__ A,
                                                 const float* __restrict__ W,
                                                 const float* __restrict__ bias,
                                                 const float* __restrict__ R,
                                                 float* __restrict__ C) {
    __shared__ float sA[64][33];
    __shared__ float sB[64][33];

    const int bm  = blockIdx.x * 64;
    const int bn  = blockIdx.y * 64;
    const int tid = threadIdx.x;
    const int tm  = (tid >> 4) << 2;   // 0..60
    const int tn  = (tid & 15) << 2;   // 0..60

    const int lr = tid >> 3;           // 0..31 (row within half-tile)
    const int lc = (tid & 7) << 2;     // 0,4,...,28 (float4 col)

    float acc[4][4] = {};

    for (int k0 = 0; k0 < SIZE_D; k0 += 32) {
#pragma unroll
        for (int p = 0; p < 2; ++p) {
            const int row = lr + p * 32;
            const float4 a4 = *reinterpret_cast<const float4*>(
                &A[(size_t)(bm + row) * SIZE_D + k0 + lc]);
            sA[row][lc + 0] = a4.x; sA[row][lc + 1] = a4.y;
            sA[row][lc + 2] = a4.z; sA[row][lc + 3] = a4.w;
            const float4 b4 = *reinterpret_cast<const float4*>(
                &W[(size_t)(bn + row) * SIZE_D + k0 + lc]);
            sB[row][lc + 0] = b4.x; sB[row][lc + 1] = b4.y;
            sB[row][lc + 2] = b4.z; sB[row][lc + 3] = b4.w;
        }
        __syncthreads();
#pragma unroll
        for (int kk = 0; kk < 32; ++kk) {
            float a[4], b[4];
#pragma unroll
            for (int i = 0; i < 4; ++i) a[i] = sA[tm + i][kk];
#pragma unroll
            for (int j = 0; j < 4; ++j) b[j] = sB[tn + j][kk];
#pragma unroll
            for (int i = 0; i < 4; ++i)
#pragma unroll
                for (int j = 0; j < 4; ++j)
                    acc[i][j] = fmaf(a[i], b[j], acc[i][j]);
        }
        __syncthreads();
    }

#pragma unroll
    for (int i = 0; i < 4; ++i) {
        const size_t row = (size_t)(bm + tm + i);
#pragma unroll
        for (int j = 0; j < 4; ++j) {
            const int col = bn + tn + j;
            float z = acc[i][j] + bias[col];
            if (RELU_RES) {
                z = R[row * SIZE_D + col] + fmaxf(z, 0.0f);
            }
            C[row * SIZE_D + col] = z;
        }
    }
}

// ---------------------------------------------------------------------------
// Attention for one (batch, head) pair per block. 512 threads = 8 waves.
// K,V tiles staged in LDS as bf16. Each wave owns 64 query rows; all softmax
// reductions are wave-local (shfl), no cross-wave reduction needed.
// Writes oh = qh + A @ vh IN PLACE into q.
// ---------------------------------------------------------------------------
__global__ __launch_bounds__(512) void attn_kernel(float* __restrict__ q,
                                                   const float* __restrict__ k,
                                                   const float* __restrict__ v) {
    __shared__ __hip_bfloat16 Ks[512][66];   // padded: stride 66 breaks bank conflicts
    __shared__ __hip_bfloat16 Vs[512][64];   // lane-contiguous reads: conflict-free
    __shared__ float wrow[8][512];           // per-wave signed-softmax weights
    __shared__ float qs[8][64];              // per-wave q row broadcast

    const int bh   = blockIdx.x;
    const int b    = bh >> 3;
    const int h    = bh & 7;
    const int tid  = threadIdx.x;
    const int wv   = tid >> 6;
    const int lane = tid & 63;

    const size_t base = ((size_t)b * SEQ) * SIZE_D + h * HDIM;

    // stage K, V -> LDS (bf16). 512*64 elems each; float4 loads.
    for (int i = tid; i < 512 * 16; i += 512) {
        const int row = i >> 4;
        const int c   = (i & 15) << 2;
        const float4 k4 = *reinterpret_cast<const float4*>(&k[base + (size_t)row * SIZE_D + c]);
        Ks[row][c + 0] = __float2bfloat16(k4.x);
        Ks[row][c + 1] = __float2bfloat16(k4.y);
        Ks[row][c + 2] = __float2bfloat16(k4.z);
        Ks[row][c + 3] = __float2bfloat16(k4.w);
        const float4 v4 = *reinterpret_cast<const float4*>(&v[base + (size_t)row * SIZE_D + c]);
        Vs[row][c + 0] = __float2bfloat16(v4.x);
        Vs[row][c + 1] = __float2bfloat16(v4.y);
        Vs[row][c + 2] = __float2bfloat16(v4.z);
        Vs[row][c + 3] = __float2bfloat16(v4.w);
    }
    __syncthreads();

    // each wave: 64 query rows
    for (int r0 = 0; r0 < 64; ++r0) {
        const int r = wv * 64 + r0;

        // load q row (lane d loads element d), broadcast via LDS
        const float qd = q[base + (size_t)r * SIZE_D + lane];
        qs[wv][lane] = qd;
        __syncthreads();   // (A) qs visible; previous iter's LDS fully consumed

        // scores: lane handles kv = jj*64 + lane, jj = 0..7
        float s[8];
#pragma unroll
        for (int jj = 0; jj < 8; ++jj) s[jj] = 0.0f;

        for (int d2 = 0; d2 < 32; ++d2) {
            const float2 qq = *reinterpret_cast<const float2*>(&qs[wv][d2 * 2]);
#pragma unroll
            for (int jj = 0; jj < 8; ++jj) {
                const __hip_bfloat162 kk =
                    *reinterpret_cast<const __hip_bfloat162*>(&Ks[jj * 64 + lane][d2 * 2]);
                s[jj] = fmaf(qq.x, __bfloat162float(kk.x), s[jj]);
                s[jj] = fmaf(qq.y, __bfloat162float(kk.y), s[jj]);
            }
        }

        // signed softmax: A = tanh(s) * softmax(sqrt(s^2+0.01))
        float u[8];
        float mloc = -1e30f;
#pragma unroll
        for (int jj = 0; jj < 8; ++jj) {
            const float sv = s[jj] * SCALE;
            s[jj] = sv;
            u[jj] = sqrtf(fmaf(sv, sv, 0.01f));
            mloc  = fmaxf(mloc, u[jj]);
        }
#pragma unroll
        for (int off = 32; off > 0; off >>= 1)
            mloc = fmaxf(mloc, __shfl_xor(mloc, off));

        float esum = 0.0f;
#pragma unroll
        for (int jj = 0; jj < 8; ++jj) {
            const float e  = __expf(u[jj] - mloc);
            esum += e;
            const float e2 = __expf(2.0f * s[jj]);
            const float th = (e2 - 1.0f) / (e2 + 1.0f);   // tanh(s)
            wrow[wv][jj * 64 + lane] = th * e;
        }
#pragma unroll
        for (int off = 32; off > 0; off >>= 1)
            esum += __shfl_xor(esum, off);

        __syncthreads();   // (B) wrow visible

        // output: lane owns dim d = lane; o[d] = sum_kv w[kv] * V[kv][d]
        float o = 0.0f;
#pragma unroll 4
        for (int kv = 0; kv < 512; ++kv) {
            o = fmaf(wrow[wv][kv], __bfloat162float(Vs[kv][lane]), o);
        }

        q[base + (size_t)r * SIZE_D + lane] = qd + o / esum;   // residual, in place
    }
}

// ---------------------------------------------------------------------------
// Row LayerNorm over 512 elems. 256 threads/block, 1 row/block, float2/thread.
// Safe in-place (each thread only touches its own 2 elements).
// ---------------------------------------------------------------------------
__global__ __launch_bounds__(256) void ln_kernel(const float* __restrict__ in,
                                                 const float* __restrict__ w,
                                                 const float* __restrict__ b,
                                                 float* __restrict__ out) {
    const int row = blockIdx.x;
    const int tid = threadIdx.x;
    const float2 x = *reinterpret_cast<const float2*>(&in[(size_t)row * SIZE_D + tid * 2]);

    float s  = x.x + x.y;
    float sq = x.x * x.x + x.y * x.y;
#pragma unroll
    for (int off = 32; off > 0; off >>= 1) {
        s  += __shfl_xor(s, off);
        sq += __shfl_xor(sq, off);
    }
    __shared__ float rs[4], rq[4];
    const int wv = tid >> 6;
    if ((tid & 63) == 0) { rs[wv] = s; rq[wv] = sq; }
    __syncthreads();
    s  = rs[0] + rs[1] + rs[2] + rs[3];
    sq = rq[0] + rq[1] + rq[2] + rq[3];

    const float mu  = s * (1.0f / SIZE_D);
    const float var = sq * (1.0f / SIZE_D) - mu * mu;
    const float rr  = rsqrtf(var + 1e-5f);

    const float2 wv2 = *reinterpret_cast<const float2*>(&w[tid * 2]);
    const float2 bv2 = *reinterpret_cast<const float2*>(&b[tid * 2]);
    float2 o;
    o.x = (x.x - mu) * rr * wv2.x + bv2.x;
    o.y = (x.y - mu) * rr * wv2.y + bv2.y;
    *reinterpret_cast<float2*>(&out[(size_t)row * SIZE_D + tid * 2]) = o;
}

// ---------------------------------------------------------------------------
extern "C" void kernel_launch(void* const* d_in, const int* in_sizes, int n_in,
                              void* d_out, int out_size, void* d_ws, size_t ws_size,
                              hipStream_t stream) {
    const float* query = (const float*)d_in[0];
    const float* keyv  = (const float*)d_in[1];
    const float* Wq    = (const float*)d_in[2];
    const float* bq    = (const float*)d_in[3];
    const float* Wk    = (const float*)d_in[4];
    const float* bk    = (const float*)d_in[5];
    const float* Wv    = (const float*)d_in[6];
    const float* bv    = (const float*)d_in[7];
    const float* Wo    = (const float*)d_in[8];
    const float* bo    = (const float*)d_in[9];
    const float* ln0w  = (const float*)d_in[10];
    const float* ln0b  = (const float*)d_in[11];
    const float* ln1w  = (const float*)d_in[12];
    const float* ln1b  = (const float*)d_in[13];
    float* out = (float*)d_out;

    const size_t NBUF = (size_t)NROWS * SIZE_D;   // 8,388,608 floats = 32 MiB
    float* qbuf = (float*)d_ws;
    float* kbuf = qbuf + NBUF;
    float* vbuf = kbuf + NBUF;

    const dim3 gg(NROWS / 64, SIZE_D / 64);       // (256, 8)

    // projections
    gemm_bias<0><<<gg, 256, 0, stream>>>(query, Wq, bq, nullptr, qbuf);
    gemm_bias<0><<<gg, 256, 0, stream>>>(keyv,  Wk, bk, nullptr, kbuf);
    gemm_bias<0><<<gg, 256, 0, stream>>>(keyv,  Wv, bv, nullptr, vbuf);

    // attention + residual (in place into qbuf)
    attn_kernel<<<BATCH * HEADS, 512, 0, stream>>>(qbuf, kbuf, vbuf);

    // LN0 (in place)
    ln_kernel<<<NROWS, 256, 0, stream>>>(qbuf, ln0w, ln0b, qbuf);

    // out-proj + ReLU + residual -> kbuf (dead after attention)
    gemm_bias<1><<<gg, 256, 0, stream>>>(qbuf, Wo, bo, qbuf, kbuf);

    // LN1 -> d_out
    ln_kernel<<<NROWS, 256, 0, stream>>>(kbuf, ln1w, ln1b, out);
}

// Round 2
// 878.748 us; speedup vs baseline: 1.9083x; 1.9083x over previous
//
#include <hip/hip_runtime.h>

#define SIZE_D 512
#define HEADS  8
#define HDIM   64
#define BATCH  32
#define SEQ    512
#define SCALE_F 0.125f   // 1/sqrt(64)
#define NROWS  (BATCH * SEQ)   // 16384

typedef __attribute__((ext_vector_type(8))) short bf16x8;
typedef __attribute__((ext_vector_type(4))) float f32x4;
typedef __attribute__((ext_vector_type(4))) unsigned int u32x4;

__device__ __forceinline__ unsigned short f2bf(float f) {
    union { float f; unsigned int u; } c{f};
    unsigned int x = c.u;
    x += 0x7fffu + ((x >> 16) & 1u);   // RNE (no NaN handling needed for this data)
    return (unsigned short)(x >> 16);
}

// ---------------------------------------------------------------------------
// GEMM: z[m,n] = dot(A[m,:], W[n,:]) + bias[n]        (A @ W^T + b)
// EPI 0: C[m,n] = z                 (f32 out)
// EPI 1: Hd[b,h,l,d] = bf16(z)      (bf16 head-major out only; C unused)
// EPI 2: C[m,n] = R[m,n] + relu(z)  (f32 out)
// ---------------------------------------------------------------------------
template <int EPI>
__global__ __launch_bounds__(256) void gemm_bias(const float* __restrict__ A,
                                                 const float* __restrict__ W,
                                                 const float* __restrict__ bias,
                                                 const float* __restrict__ R,
                                                 float* __restrict__ C,
                                                 unsigned short* __restrict__ Hd) {
    __shared__ float sA[64][33];
    __shared__ float sB[64][33];

    const int bm  = blockIdx.x * 64;
    const int bn  = blockIdx.y * 64;
    const int tid = threadIdx.x;
    const int tm  = (tid >> 4) << 2;
    const int tn  = (tid & 15) << 2;

    const int lr = tid >> 3;
    const int lc = (tid & 7) << 2;

    float acc[4][4] = {};

    for (int k0 = 0; k0 < SIZE_D; k0 += 32) {
#pragma unroll
        for (int p = 0; p < 2; ++p) {
            const int row = lr + p * 32;
            const float4 a4 = *reinterpret_cast<const float4*>(
                &A[(size_t)(bm + row) * SIZE_D + k0 + lc]);
            sA[row][lc + 0] = a4.x; sA[row][lc + 1] = a4.y;
            sA[row][lc + 2] = a4.z; sA[row][lc + 3] = a4.w;
            const float4 b4 = *reinterpret_cast<const float4*>(
                &W[(size_t)(bn + row) * SIZE_D + k0 + lc]);
            sB[row][lc + 0] = b4.x; sB[row][lc + 1] = b4.y;
            sB[row][lc + 2] = b4.z; sB[row][lc + 3] = b4.w;
        }
        __syncthreads();
#pragma unroll
        for (int kk = 0; kk < 32; ++kk) {
            float a[4], b[4];
#pragma unroll
            for (int i = 0; i < 4; ++i) a[i] = sA[tm + i][kk];
#pragma unroll
            for (int j = 0; j < 4; ++j) b[j] = sB[tn + j][kk];
#pragma unroll
            for (int i = 0; i < 4; ++i)
#pragma unroll
                for (int j = 0; j < 4; ++j)
                    acc[i][j] = fmaf(a[i], b[j], acc[i][j]);
        }
        __syncthreads();
    }

#pragma unroll
    for (int i = 0; i < 4; ++i) {
        const int r  = bm + tm + i;
#pragma unroll
        for (int j = 0; j < 4; ++j) {
            const int col = bn + tn + j;
            float z = acc[i][j] + bias[col];
            if (EPI == 2) {
                z = R[(size_t)r * SIZE_D + col] + fmaxf(z, 0.0f);
            }
            if (EPI == 1) {
                const int b_ = r >> 9, l = r & 511;
                const int h  = col >> 6, dd = col & 63;
                Hd[(((size_t)b_ * HEADS + h) * SEQ + l) * HDIM + dd] = f2bf(z);
            } else {
                C[(size_t)r * SIZE_D + col] = z;
            }
        }
    }
}

// ---------------------------------------------------------------------------
// MFMA attention, one (b,h) per block, 8 waves x 64 Q-rows.
//   S = Q K^T * SCALE ; W = tanh(S)*exp(sqrt(S^2+0.01)) ; O = q + (W V)/sum(exp)
// Q: f32 from qbuf (converted in-reg). K: global bf16 head-major (L1/L2 hot).
// V: staged transposed in LDS (XOR-swizzled). W: per-wave LDS round-trip to
// transpose MFMA C-layout -> A-layout. Residual written in-place into qbuf.
// ---------------------------------------------------------------------------
__global__ __launch_bounds__(512, 2) void attn_mfma(float* __restrict__ q,
                                                    const unsigned short* __restrict__ Kh,
                                                    const unsigned short* __restrict__ Vh) {
    __shared__ __align__(16) unsigned short VtL[64 * 512];   // 64KB, Vt[d][kv], swizzled
    __shared__ __align__(16) unsigned short WL[8][64 * 64];  // 64KB, per-wave W scratch

    const int tid  = threadIdx.x;
    const int wv   = tid >> 6;
    const int lane = tid & 63;
    const int bh   = blockIdx.x;
    const int b    = bh >> 3;
    const int h    = bh & 7;

    const unsigned short* Kb = Kh + (size_t)bh * (SEQ * HDIM);
    const unsigned short* Vb = Vh + (size_t)bh * (SEQ * HDIM);
    float* qb = q + (size_t)b * (SEQ * SIZE_D) + h * HDIM;

    // ---- stage V transposed into VtL (bounce tile overlays WL) ----
    unsigned short* Tb = &WL[0][0];    // [64][66] ushort bounce
    for (int c = 0; c < 8; ++c) {
        {   // phase A: global V rows -> bounce (row-major, stride 66)
            const int kv = tid >> 3;
            const int d8 = (tid & 7) * 8;
            u32x4 rv = *reinterpret_cast<const u32x4*>(Vb + (size_t)(c * 64 + kv) * HDIM + d8);
            const unsigned short* rs = reinterpret_cast<const unsigned short*>(&rv);
            __syncthreads();           // previous phase B fully consumed Tb
            unsigned short* dst = &Tb[kv * 66 + d8];
#pragma unroll
            for (int j = 0; j < 8; ++j) dst[j] = rs[j];
        }
        __syncthreads();
        {   // phase B: bounce columns -> VtL rows (swizzled)
            const int d  = tid >> 3;
            const int k8 = (tid & 7) * 8;
            unsigned short tmp[8];
#pragma unroll
            for (int j = 0; j < 8; ++j) tmp[j] = Tb[(k8 + j) * 66 + d];
            int byte = d * 1024 + (c * 64 + k8) * 2;
            byte ^= (d & 7) << 4;
            *reinterpret_cast<u32x4*>(reinterpret_cast<char*>(VtL) + byte) =
                *reinterpret_cast<const u32x4*>(tmp);
        }
    }
    __syncthreads();

    // ---- per-wave Q fragments (A-layout: row=lane&15, k=8*(lane>>4)+j) ----
    const int m0 = wv * 64;
    bf16x8 qf[4][2];
#pragma unroll
    for (int mt = 0; mt < 4; ++mt)
#pragma unroll
        for (int kc = 0; kc < 2; ++kc) {
            const int m = m0 + mt * 16 + (lane & 15);
            const int d = kc * 32 + (lane >> 4) * 8;
            const float* src = qb + (size_t)m * SIZE_D + d;
            const float4 a0 = *reinterpret_cast<const float4*>(src);
            const float4 a1 = *reinterpret_cast<const float4*>(src + 4);
            union { bf16x8 v; unsigned short s[8]; } u;
            u.s[0] = f2bf(a0.x); u.s[1] = f2bf(a0.y);
            u.s[2] = f2bf(a0.z); u.s[3] = f2bf(a0.w);
            u.s[4] = f2bf(a1.x); u.s[5] = f2bf(a1.y);
            u.s[6] = f2bf(a1.z); u.s[7] = f2bf(a1.w);
            qf[mt][kc] = u.v;
        }

    unsigned short* myW = &WL[wv][0];
    f32x4 oacc[4][4];
    float esum[4][4];
#pragma unroll
    for (int mt = 0; mt < 4; ++mt)
#pragma unroll
        for (int x = 0; x < 4; ++x) {
            oacc[mt][x] = (f32x4){0.f, 0.f, 0.f, 0.f};
            esum[mt][x] = 0.f;
        }

    for (int t = 0; t < 8; ++t) {
        const int kv0 = t * 64;
        f32x4 sacc[4][4];
#pragma unroll
        for (int mt = 0; mt < 4; ++mt)
#pragma unroll
            for (int nt = 0; nt < 4; ++nt) sacc[mt][nt] = (f32x4){0.f, 0.f, 0.f, 0.f};

#pragma unroll
        for (int kc = 0; kc < 2; ++kc) {
            bf16x8 kf[4];
#pragma unroll
            for (int nt = 0; nt < 4; ++nt) {   // B-layout: col=lane&15, k=8*(lane>>4)+j
                const int kv = kv0 + nt * 16 + (lane & 15);
                const int d  = kc * 32 + (lane >> 4) * 8;
                union { u32x4 u; bf16x8 v; } cv;
                cv.u = *reinterpret_cast<const u32x4*>(Kb + (size_t)kv * HDIM + d);
                kf[nt] = cv.v;
            }
#pragma unroll
            for (int mt = 0; mt < 4; ++mt)
#pragma unroll
                for (int nt = 0; nt < 4; ++nt)
                    sacc[mt][nt] = __builtin_amdgcn_mfma_f32_16x16x32_bf16(
                        qf[mt][kc], kf[nt], sacc[mt][nt], 0, 0, 0);
        }

        // transform scores -> weights, write to per-wave W scratch (swizzled)
#pragma unroll
        for (int mt = 0; mt < 4; ++mt)
#pragma unroll
            for (int nt = 0; nt < 4; ++nt)
#pragma unroll
                for (int r = 0; r < 4; ++r) {
                    const float s  = sacc[mt][nt][r] * SCALE_F;
                    const float u  = sqrtf(fmaf(s, s, 0.01f));
                    const float e  = __expf(u);
                    esum[mt][r] += e;
                    const float e2 = __expf(-2.0f * fabsf(s));
                    float th = (1.0f - e2) / (1.0f + e2);
                    th = (s < 0.0f) ? -th : th;
                    const int row = mt * 16 + (lane >> 4) * 4 + r;   // C-layout row
                    const int col = nt * 16 + (lane & 15);           // C-layout col
                    int byte = row * 128 + col * 2;
                    byte ^= (row & 7) << 4;
                    *reinterpret_cast<unsigned short*>(reinterpret_cast<char*>(myW) + byte) =
                        f2bf(th * e);
                }

        // PV: O += W * V
#pragma unroll
        for (int kc2 = 0; kc2 < 2; ++kc2) {
            bf16x8 wf[4], vf[4];
#pragma unroll
            for (int mt = 0; mt < 4; ++mt) {   // A-frag of W: row=lane&15
                const int row = mt * 16 + (lane & 15);
                int byte = row * 128 + kc2 * 64 + (lane >> 4) * 16;
                byte ^= (row & 7) << 4;
                union { u32x4 u; bf16x8 v; } cv;
                cv.u = *reinterpret_cast<const u32x4*>(reinterpret_cast<char*>(myW) + byte);
                wf[mt] = cv.v;
            }
#pragma unroll
            for (int dt = 0; dt < 4; ++dt) {   // B-frag of V from Vt: col=lane&15 (=d)
                const int d = dt * 16 + (lane & 15);
                int byte = d * 1024 + (kv0 + kc2 * 32 + (lane >> 4) * 8) * 2;
                byte ^= (d & 7) << 4;
                union { u32x4 u; bf16x8 v; } cv;
                cv.u = *reinterpret_cast<const u32x4*>(reinterpret_cast<char*>(VtL) + byte);
                vf[dt] = cv.v;
            }
#pragma unroll
            for (int mt = 0; mt < 4; ++mt)
#pragma unroll
                for (int dt = 0; dt < 4; ++dt)
                    oacc[mt][dt] = __builtin_amdgcn_mfma_f32_16x16x32_bf16(
                        wf[mt], vf[dt], oacc[mt][dt], 0, 0, 0);
        }
    }

    // epilogue: normalize, residual, in-place write
    float rden[4][4];
#pragma unroll
    for (int mt = 0; mt < 4; ++mt)
#pragma unroll
        for (int r = 0; r < 4; ++r) {
            float es = esum[mt][r];
#pragma unroll
            for (int msk = 8; msk >= 1; msk >>= 1) es += __shfl_xor(es, msk);
            rden[mt][r] = 1.0f / es;
        }
#pragma unroll
    for (int mt = 0; mt < 4; ++mt)
#pragma unroll
        for (int dt = 0; dt < 4; ++dt)
#pragma unroll
            for (int r = 0; r < 4; ++r) {
                const int m = m0 + mt * 16 + (lane >> 4) * 4 + r;
                const int d = dt * 16 + (lane & 15);
                float* p = qb + (size_t)m * SIZE_D + d;
                *p = *p + oacc[mt][dt][r] * rden[mt][r];
            }
}

// ---------------------------------------------------------------------------
// Row LayerNorm over 512 elems.
// ---------------------------------------------------------------------------
__global__ __launch_bounds__(256) void ln_kernel(const float* __restrict__ in,
                                                 const float* __restrict__ w,
                                                 const float* __restrict__ b,
                                                 float* __restrict__ out) {
    const int row = blockIdx.x;
    const int tid = threadIdx.x;
    const float2 x = *reinterpret_cast<const float2*>(&in[(size_t)row * SIZE_D + tid * 2]);

    float s  = x.x + x.y;
    float sq = x.x * x.x + x.y * x.y;
#pragma unroll
    for (int off = 32; off > 0; off >>= 1) {
        s  += __shfl_xor(s, off);
        sq += __shfl_xor(sq, off);
    }
    __shared__ float rs[4], rq[4];
    const int wv = tid >> 6;
    if ((tid & 63) == 0) { rs[wv] = s; rq[wv] = sq; }
    __syncthreads();
    s  = rs[0] + rs[1] + rs[2] + rs[3];
    sq = rq[0] + rq[1] + rq[2] + rq[3];

    const float mu  = s * (1.0f / SIZE_D);
    const float var = sq * (1.0f / SIZE_D) - mu * mu;
    const float rr  = rsqrtf(var + 1e-5f);

    const float2 wv2 = *reinterpret_cast<const float2*>(&w[tid * 2]);
    const float2 bv2 = *reinterpret_cast<const float2*>(&b[tid * 2]);
    float2 o;
    o.x = (x.x - mu) * rr * wv2.x + bv2.x;
    o.y = (x.y - mu) * rr * wv2.y + bv2.y;
    *reinterpret_cast<float2*>(&out[(size_t)row * SIZE_D + tid * 2]) = o;
}

// ---------------------------------------------------------------------------
extern "C" void kernel_launch(void* const* d_in, const int* in_sizes, int n_in,
                              void* d_out, int out_size, void* d_ws, size_t ws_size,
                              hipStream_t stream) {
    const float* query = (const float*)d_in[0];
    const float* keyv  = (const float*)d_in[1];
    const float* Wq    = (const float*)d_in[2];
    const float* bq    = (const float*)d_in[3];
    const float* Wk    = (const float*)d_in[4];
    const float* bk    = (const float*)d_in[5];
    const float* Wv    = (const float*)d_in[6];
    const float* bv    = (const float*)d_in[7];
    const float* Wo    = (const float*)d_in[8];
    const float* bo    = (const float*)d_in[9];
    const float* ln0w  = (const float*)d_in[10];
    const float* ln0b  = (const float*)d_in[11];
    const float* ln1w  = (const float*)d_in[12];
    const float* ln1b  = (const float*)d_in[13];
    float* out = (float*)d_out;

    // workspace layout (64 MB total):
    //   [0,32MB)  qbuf f32
    //   [32,48MB) Kh bf16 head-major   } obuf f32 (out-proj dest) aliases
    //   [48,64MB) Vh bf16 head-major   } [32,64MB) after attention is done
    char* ws = (char*)d_ws;
    float*          qbuf = (float*)ws;
    unsigned short* Kh   = (unsigned short*)(ws + (size_t)(32 << 20));
    unsigned short* Vh   = (unsigned short*)(ws + (size_t)(48 << 20));
    float*          obuf = (float*)(ws + (size_t)(32 << 20));

    const dim3 gg(NROWS / 64, SIZE_D / 64);   // (256, 8)

    gemm_bias<0><<<gg, 256, 0, stream>>>(query, Wq, bq, nullptr, qbuf, nullptr);
    gemm_bias<1><<<gg, 256, 0, stream>>>(keyv,  Wk, bk, nullptr, nullptr, Kh);
    gemm_bias<1><<<gg, 256, 0, stream>>>(keyv,  Wv, bv, nullptr, nullptr, Vh);

    attn_mfma<<<BATCH * HEADS, 512, 0, stream>>>(qbuf, Kh, Vh);

    ln_kernel<<<NROWS, 256, 0, stream>>>(qbuf, ln0w, ln0b, qbuf);
    gemm_bias<2><<<gg, 256, 0, stream>>>(qbuf, Wo, bo, qbuf, obuf, nullptr);
    ln_kernel<<<NROWS, 256, 0, stream>>>(obuf, ln1w, ln1b, out);
}

// Round 3
// 260.673 us; speedup vs baseline: 6.4330x; 3.3711x over previous
//
#include <hip/hip_runtime.h>

#define SIZE_D 512
#define HEADS  8
#define HDIM   64
#define BATCH  32
#define SEQ    512
#define SCALE_F 0.125f   // 1/sqrt(64)
#define NROWS  (BATCH * SEQ)   // 16384

typedef __attribute__((ext_vector_type(8))) short bf16x8;
typedef __attribute__((ext_vector_type(4))) float f32x4;
typedef __attribute__((ext_vector_type(4))) unsigned int u32x4;

__device__ __forceinline__ unsigned short f2bf(float f) {
    union { float f; unsigned int u; } c{f};
    unsigned int x = c.u;
    x += 0x7fffu + ((x >> 16) & 1u);   // RNE
    return (unsigned short)(x >> 16);
}

__device__ __forceinline__ void gload_lds16(const unsigned short* g, unsigned short* l) {
    __builtin_amdgcn_global_load_lds(
        (const __attribute__((address_space(1))) unsigned int*)g,
        (__attribute__((address_space(3))) unsigned int*)l, 16, 0, 0);
}

// ---------------------------------------------------------------------------
// f32 -> bf16 convert, grid-stride, float4 in / ushort4 out
// ---------------------------------------------------------------------------
__global__ __launch_bounds__(256) void cvt_bf16(const float* __restrict__ s,
                                                unsigned short* __restrict__ d, int n) {
    const int stride = gridDim.x * blockDim.x * 4;
    for (int i = (blockIdx.x * blockDim.x + threadIdx.x) * 4; i < n; i += stride) {
        const float4 v = *reinterpret_cast<const float4*>(s + i);
        ushort4 o;
        o.x = f2bf(v.x); o.y = f2bf(v.y); o.z = f2bf(v.z); o.w = f2bf(v.w);
        *reinterpret_cast<ushort4*>(d + i) = o;
    }
}

// ---------------------------------------------------------------------------
// MFMA GEMM: z[m,n] = dot(A[m,:], W[n,:]) + bias[n]      (A @ W^T + b)
// A: [M][512] bf16 row-major, W: [512][512] bf16 row-major.
// 128x128 tile, BK=64, 256 thr = 4 waves (2x2 of 64x64), 16x16x32 MFMA.
// global_load_lds(16B) staging, source pre-swizzled / ds_read swizzled
// (byte ^= (row&7)<<4) to kill the 128B-row-stride bank conflict.
// EPI 0: C[m,n] = z (f32)
// EPI 1: Hd[b,h,l,d] = bf16(z) head-major
// EPI 2: C[m,n] = R[m,n] + relu(z) (f32)
// ---------------------------------------------------------------------------
template <int EPI>
__global__ __launch_bounds__(256, 2) void gemm_mfma(const unsigned short* __restrict__ A,
                                                    const unsigned short* __restrict__ W,
                                                    const float* __restrict__ bias,
                                                    const float* __restrict__ R,
                                                    float* __restrict__ C,
                                                    unsigned short* __restrict__ Hd) {
    __shared__ __align__(16) unsigned short Ad[2][128 * 64];
    __shared__ __align__(16) unsigned short Bd[2][128 * 64];

    const int tid  = threadIdx.x;
    const int wv   = tid >> 6;
    const int lane = tid & 63;
    const int bm   = blockIdx.x * 128;
    const int bn   = blockIdx.y * 128;
    const int wr   = wv >> 1;       // wave row (0..1)
    const int wc   = wv & 1;        // wave col (0..1)

    // ---- staging: wave wv covers rows [wv*32, wv*32+32), 4 x 1KB issues ----
    auto stage = [&](int buf, int t) {
        const int k0 = t * 64;
#pragma unroll
        for (int i = 0; i < 4; ++i) {
            const int o     = (wv * 32 + i * 8) * 128 + lane * 16;  // linear byte off
            const int row   = o >> 7;
            const int inrow = (o & 127) ^ ((row & 7) << 4);         // inverse swizzle
            const int col   = inrow >> 1;                            // bf16 elem in BK
            gload_lds16(A + (size_t)(bm + row) * SIZE_D + k0 + col, &Ad[buf][o >> 1]);
            gload_lds16(W + (size_t)(bn + row) * SIZE_D + k0 + col, &Bd[buf][o >> 1]);
        }
    };

    f32x4 acc[4][4];
#pragma unroll
    for (int mt = 0; mt < 4; ++mt)
#pragma unroll
        for (int nt = 0; nt < 4; ++nt) acc[mt][nt] = (f32x4){0.f, 0.f, 0.f, 0.f};

    stage(0, 0);
    __syncthreads();
    int cur = 0;

    for (int t = 0; t < 8; ++t) {
        if (t < 7) stage(cur ^ 1, t + 1);

        bf16x8 af[2][4], bfr[2][4];
#pragma unroll
        for (int kc = 0; kc < 2; ++kc) {
#pragma unroll
            for (int mt = 0; mt < 4; ++mt) {
                const int r = wr * 64 + mt * 16 + (lane & 15);
                int byte = r * 128 + kc * 64 + (lane >> 4) * 16;
                byte ^= (r & 7) << 4;
                af[kc][mt] = *reinterpret_cast<const bf16x8*>(
                    reinterpret_cast<const char*>(&Ad[cur][0]) + byte);
            }
#pragma unroll
            for (int nt = 0; nt < 4; ++nt) {
                const int r = wc * 64 + nt * 16 + (lane & 15);
                int byte = r * 128 + kc * 64 + (lane >> 4) * 16;
                byte ^= (r & 7) << 4;
                bfr[kc][nt] = *reinterpret_cast<const bf16x8*>(
                    reinterpret_cast<const char*>(&Bd[cur][0]) + byte);
            }
        }
#pragma unroll
        for (int kc = 0; kc < 2; ++kc)
#pragma unroll
            for (int mt = 0; mt < 4; ++mt)
#pragma unroll
                for (int nt = 0; nt < 4; ++nt)
                    acc[mt][nt] = __builtin_amdgcn_mfma_f32_16x16x32_bf16(
                        af[kc][mt], bfr[kc][nt], acc[mt][nt], 0, 0, 0);

        __syncthreads();   // drains vmcnt for next buffer + protects cur reuse
        cur ^= 1;
    }

    // ---- epilogue (C-layout: col = lane&15, row = (lane>>4)*4 + r) ----
#pragma unroll
    for (int nt = 0; nt < 4; ++nt) {
        const int col  = bn + wc * 64 + nt * 16 + (lane & 15);
        const float bc = bias[col];
#pragma unroll
        for (int mt = 0; mt < 4; ++mt) {
            const int row0 = bm + wr * 64 + mt * 16 + (lane >> 4) * 4;
#pragma unroll
            for (int r = 0; r < 4; ++r) {
                const int row = row0 + r;
                float z = acc[mt][nt][r] + bc;
                if (EPI == 2) {
                    z = R[(size_t)row * SIZE_D + col] + fmaxf(z, 0.0f);
                }
                if (EPI == 1) {
                    const int b_ = row >> 9, l = row & 511;
                    const int h  = col >> 6, dd = col & 63;
                    Hd[(((size_t)b_ * HEADS + h) * SEQ + l) * HDIM + dd] = f2bf(z);
                } else {
                    C[(size_t)row * SIZE_D + col] = z;
                }
            }
        }
    }
}

// ---------------------------------------------------------------------------
// MFMA attention, one (b,h) per block, 8 waves x 64 Q-rows. (unchanged)
// ---------------------------------------------------------------------------
__global__ __launch_bounds__(512, 2) void attn_mfma(float* __restrict__ q,
                                                    const unsigned short* __restrict__ Kh,
                                                    const unsigned short* __restrict__ Vh) {
    __shared__ __align__(16) unsigned short VtL[64 * 512];   // Vt[d][kv], swizzled
    __shared__ __align__(16) unsigned short WL[8][64 * 64];  // per-wave W scratch

    const int tid  = threadIdx.x;
    const int wv   = tid >> 6;
    const int lane = tid & 63;
    const int bh   = blockIdx.x;
    const int b    = bh >> 3;
    const int h    = bh & 7;

    const unsigned short* Kb = Kh + (size_t)bh * (SEQ * HDIM);
    const unsigned short* Vb = Vh + (size_t)bh * (SEQ * HDIM);
    float* qb = q + (size_t)b * (SEQ * SIZE_D) + h * HDIM;

    // ---- stage V transposed into VtL (bounce tile overlays WL) ----
    unsigned short* Tb = &WL[0][0];    // [64][66] ushort bounce
    for (int c = 0; c < 8; ++c) {
        {
            const int kv = tid >> 3;
            const int d8 = (tid & 7) * 8;
            u32x4 rv = *reinterpret_cast<const u32x4*>(Vb + (size_t)(c * 64 + kv) * HDIM + d8);
            const unsigned short* rs = reinterpret_cast<const unsigned short*>(&rv);
            __syncthreads();
            unsigned short* dst = &Tb[kv * 66 + d8];
#pragma unroll
            for (int j = 0; j < 8; ++j) dst[j] = rs[j];
        }
        __syncthreads();
        {
            const int d  = tid >> 3;
            const int k8 = (tid & 7) * 8;
            unsigned short tmp[8];
#pragma unroll
            for (int j = 0; j < 8; ++j) tmp[j] = Tb[(k8 + j) * 66 + d];
            int byte = d * 1024 + (c * 64 + k8) * 2;
            byte ^= (d & 7) << 4;
            *reinterpret_cast<u32x4*>(reinterpret_cast<char*>(VtL) + byte) =
                *reinterpret_cast<const u32x4*>(tmp);
        }
    }
    __syncthreads();

    const int m0 = wv * 64;
    bf16x8 qf[4][2];
#pragma unroll
    for (int mt = 0; mt < 4; ++mt)
#pragma unroll
        for (int kc = 0; kc < 2; ++kc) {
            const int m = m0 + mt * 16 + (lane & 15);
            const int d = kc * 32 + (lane >> 4) * 8;
            const float* src = qb + (size_t)m * SIZE_D + d;
            const float4 a0 = *reinterpret_cast<const float4*>(src);
            const float4 a1 = *reinterpret_cast<const float4*>(src + 4);
            union { bf16x8 v; unsigned short s[8]; } u;
            u.s[0] = f2bf(a0.x); u.s[1] = f2bf(a0.y);
            u.s[2] = f2bf(a0.z); u.s[3] = f2bf(a0.w);
            u.s[4] = f2bf(a1.x); u.s[5] = f2bf(a1.y);
            u.s[6] = f2bf(a1.z); u.s[7] = f2bf(a1.w);
            qf[mt][kc] = u.v;
        }

    unsigned short* myW = &WL[wv][0];
    f32x4 oacc[4][4];
    float esum[4][4];
#pragma unroll
    for (int mt = 0; mt < 4; ++mt)
#pragma unroll
        for (int x = 0; x < 4; ++x) {
            oacc[mt][x] = (f32x4){0.f, 0.f, 0.f, 0.f};
            esum[mt][x] = 0.f;
        }

    for (int t = 0; t < 8; ++t) {
        const int kv0 = t * 64;
        f32x4 sacc[4][4];
#pragma unroll
        for (int mt = 0; mt < 4; ++mt)
#pragma unroll
            for (int nt = 0; nt < 4; ++nt) sacc[mt][nt] = (f32x4){0.f, 0.f, 0.f, 0.f};

#pragma unroll
        for (int kc = 0; kc < 2; ++kc) {
            bf16x8 kf[4];
#pragma unroll
            for (int nt = 0; nt < 4; ++nt) {
                const int kv = kv0 + nt * 16 + (lane & 15);
                const int d  = kc * 32 + (lane >> 4) * 8;
                union { u32x4 u; bf16x8 v; } cv;
                cv.u = *reinterpret_cast<const u32x4*>(Kb + (size_t)kv * HDIM + d);
                kf[nt] = cv.v;
            }
#pragma unroll
            for (int mt = 0; mt < 4; ++mt)
#pragma unroll
                for (int nt = 0; nt < 4; ++nt)
                    sacc[mt][nt] = __builtin_amdgcn_mfma_f32_16x16x32_bf16(
                        qf[mt][kc], kf[nt], sacc[mt][nt], 0, 0, 0);
        }

#pragma unroll
        for (int mt = 0; mt < 4; ++mt)
#pragma unroll
            for (int nt = 0; nt < 4; ++nt)
#pragma unroll
                for (int r = 0; r < 4; ++r) {
                    const float s  = sacc[mt][nt][r] * SCALE_F;
                    const float u  = sqrtf(fmaf(s, s, 0.01f));
                    const float e  = __expf(u);
                    esum[mt][r] += e;
                    const float e2 = __expf(-2.0f * fabsf(s));
                    float th = (1.0f - e2) / (1.0f + e2);
                    th = (s < 0.0f) ? -th : th;
                    const int row = mt * 16 + (lane >> 4) * 4 + r;
                    const int col = nt * 16 + (lane & 15);
                    int byte = row * 128 + col * 2;
                    byte ^= (row & 7) << 4;
                    *reinterpret_cast<unsigned short*>(reinterpret_cast<char*>(myW) + byte) =
                        f2bf(th * e);
                }

#pragma unroll
        for (int kc2 = 0; kc2 < 2; ++kc2) {
            bf16x8 wf[4], vf[4];
#pragma unroll
            for (int mt = 0; mt < 4; ++mt) {
                const int row = mt * 16 + (lane & 15);
                int byte = row * 128 + kc2 * 64 + (lane >> 4) * 16;
                byte ^= (row & 7) << 4;
                union { u32x4 u; bf16x8 v; } cv;
                cv.u = *reinterpret_cast<const u32x4*>(reinterpret_cast<char*>(myW) + byte);
                wf[mt] = cv.v;
            }
#pragma unroll
            for (int dt = 0; dt < 4; ++dt) {
                const int d = dt * 16 + (lane & 15);
                int byte = d * 1024 + (kv0 + kc2 * 32 + (lane >> 4) * 8) * 2;
                byte ^= (d & 7) << 4;
                union { u32x4 u; bf16x8 v; } cv;
                cv.u = *reinterpret_cast<const u32x4*>(reinterpret_cast<char*>(VtL) + byte);
                vf[dt] = cv.v;
            }
#pragma unroll
            for (int mt = 0; mt < 4; ++mt)
#pragma unroll
                for (int dt = 0; dt < 4; ++dt)
                    oacc[mt][dt] = __builtin_amdgcn_mfma_f32_16x16x32_bf16(
                        wf[mt], vf[dt], oacc[mt][dt], 0, 0, 0);
        }
    }

    float rden[4][4];
#pragma unroll
    for (int mt = 0; mt < 4; ++mt)
#pragma unroll
        for (int r = 0; r < 4; ++r) {
            float es = esum[mt][r];
#pragma unroll
            for (int msk = 8; msk >= 1; msk >>= 1) es += __shfl_xor(es, msk);
            rden[mt][r] = 1.0f / es;
        }
#pragma unroll
    for (int mt = 0; mt < 4; ++mt)
#pragma unroll
        for (int dt = 0; dt < 4; ++dt)
#pragma unroll
            for (int r = 0; r < 4; ++r) {
                const int m = m0 + mt * 16 + (lane >> 4) * 4 + r;
                const int d = dt * 16 + (lane & 15);
                float* p = qb + (size_t)m * SIZE_D + d;
                *p = *p + oacc[mt][dt][r] * rden[mt][r];
            }
}

// ---------------------------------------------------------------------------
// Row LayerNorm over 512 elems; optional extra bf16 output.
// ---------------------------------------------------------------------------
template <int BF16OUT>
__global__ __launch_bounds__(256) void ln_kernel(const float* __restrict__ in,
                                                 const float* __restrict__ w,
                                                 const float* __restrict__ b,
                                                 float* __restrict__ out,
                                                 unsigned short* __restrict__ outb) {
    const int row = blockIdx.x;
    const int tid = threadIdx.x;
    const float2 x = *reinterpret_cast<const float2*>(&in[(size_t)row * SIZE_D + tid * 2]);

    float s  = x.x + x.y;
    float sq = x.x * x.x + x.y * x.y;
#pragma unroll
    for (int off = 32; off > 0; off >>= 1) {
        s  += __shfl_xor(s, off);
        sq += __shfl_xor(sq, off);
    }
    __shared__ float rs[4], rq[4];
    const int wv = tid >> 6;
    if ((tid & 63) == 0) { rs[wv] = s; rq[wv] = sq; }
    __syncthreads();
    s  = rs[0] + rs[1] + rs[2] + rs[3];
    sq = rq[0] + rq[1] + rq[2] + rq[3];

    const float mu  = s * (1.0f / SIZE_D);
    const float var = sq * (1.0f / SIZE_D) - mu * mu;
    const float rr  = rsqrtf(var + 1e-5f);

    const float2 wv2 = *reinterpret_cast<const float2*>(&w[tid * 2]);
    const float2 bv2 = *reinterpret_cast<const float2*>(&b[tid * 2]);
    float2 o;
    o.x = (x.x - mu) * rr * wv2.x + bv2.x;
    o.y = (x.y - mu) * rr * wv2.y + bv2.y;
    *reinterpret_cast<float2*>(&out[(size_t)row * SIZE_D + tid * 2]) = o;
    if (BF16OUT) {
        ushort2 ob;
        ob.x = f2bf(o.x); ob.y = f2bf(o.y);
        *reinterpret_cast<ushort2*>(&outb[(size_t)row * SIZE_D + tid * 2]) = ob;
    }
}

// ---------------------------------------------------------------------------
extern "C" void kernel_launch(void* const* d_in, const int* in_sizes, int n_in,
                              void* d_out, int out_size, void* d_ws, size_t ws_size,
                              hipStream_t stream) {
    const float* query = (const float*)d_in[0];
    const float* keyv  = (const float*)d_in[1];
    const float* Wq    = (const float*)d_in[2];
    const float* bq    = (const float*)d_in[3];
    const float* Wk    = (const float*)d_in[4];
    const float* bk    = (const float*)d_in[5];
    const float* Wv    = (const float*)d_in[6];
    const float* bv    = (const float*)d_in[7];
    const float* Wo    = (const float*)d_in[8];
    const float* bo    = (const float*)d_in[9];
    const float* ln0w  = (const float*)d_in[10];
    const float* ln0b  = (const float*)d_in[11];
    const float* ln1w  = (const float*)d_in[12];
    const float* ln1b  = (const float*)d_in[13];
    float* out = (float*)d_out;

    // workspace (96 MB):
    //   [ 0,32) qbuf f32
    //   [32,48) Kh bf16   \ obuf f32 aliases [32,64) after attention
    //   [48,64) Vh bf16   /
    //   [64,80) Qbf bf16 (query)
    //   [80,96) KVbf bf16 (key_value)  -> reused as Xbf (ln0 bf16) after K/V GEMMs
    // d_out (32 MB): first 2 MB = bf16 weights (dead before LN1 writes out)
    char* ws = (char*)d_ws;
    float*          qbuf = (float*)ws;
    unsigned short* Kh   = (unsigned short*)(ws + ((size_t)32 << 20));
    unsigned short* Vh   = (unsigned short*)(ws + ((size_t)48 << 20));
    float*          obuf = (float*)(ws + ((size_t)32 << 20));
    unsigned short* Qbf  = (unsigned short*)(ws + ((size_t)64 << 20));
    unsigned short* KVbf = (unsigned short*)(ws + ((size_t)80 << 20));
    unsigned short* Xbf  = KVbf;

    unsigned short* Wbf  = (unsigned short*)d_out;
    unsigned short* WqB = Wbf;
    unsigned short* WkB = Wbf + 262144;
    unsigned short* WvB = Wbf + 524288;
    unsigned short* WoB = Wbf + 786432;

    const int NACT = NROWS * SIZE_D;      // 8,388,608
    const int NW   = SIZE_D * SIZE_D;     // 262,144

    cvt_bf16<<<2048, 256, 0, stream>>>(query, Qbf, NACT);
    cvt_bf16<<<2048, 256, 0, stream>>>(keyv, KVbf, NACT);
    cvt_bf16<<<256, 256, 0, stream>>>(Wq, WqB, NW);
    cvt_bf16<<<256, 256, 0, stream>>>(Wk, WkB, NW);
    cvt_bf16<<<256, 256, 0, stream>>>(Wv, WvB, NW);
    cvt_bf16<<<256, 256, 0, stream>>>(Wo, WoB, NW);

    const dim3 gg(NROWS / 128, SIZE_D / 128);   // (128, 4)

    gemm_mfma<0><<<gg, 256, 0, stream>>>(Qbf,  WqB, bq, nullptr, qbuf, nullptr);
    gemm_mfma<1><<<gg, 256, 0, stream>>>(KVbf, WkB, bk, nullptr, nullptr, Kh);
    gemm_mfma<1><<<gg, 256, 0, stream>>>(KVbf, WvB, bv, nullptr, nullptr, Vh);

    attn_mfma<<<BATCH * HEADS, 512, 0, stream>>>(qbuf, Kh, Vh);

    ln_kernel<1><<<NROWS, 256, 0, stream>>>(qbuf, ln0w, ln0b, qbuf, Xbf);
    gemm_mfma<2><<<gg, 256, 0, stream>>>(Xbf, WoB, bo, qbuf, obuf, nullptr);
    ln_kernel<0><<<NROWS, 256, 0, stream>>>(obuf, ln1w, ln1b, out, nullptr);
}

// Round 4
// 180.779 us; speedup vs baseline: 9.2761x; 1.4419x over previous
//
#include <hip/hip_runtime.h>

#define SIZE_D 512
#define HEADS  8
#define HDIM   64
#define BATCH  32
#define SEQ    512
#define SCALE_F 0.125f   // 1/sqrt(64)
#define NROWS  (BATCH * SEQ)   // 16384

typedef __attribute__((ext_vector_type(8))) short bf16x8;
typedef __attribute__((ext_vector_type(4))) float f32x4;
typedef __attribute__((ext_vector_type(4))) unsigned int u32x4;

__device__ __forceinline__ unsigned short f2bf(float f) {
    union { float f; unsigned int u; } c{f};
    unsigned int x = c.u;
    x += 0x7fffu + ((x >> 16) & 1u);   // RNE
    return (unsigned short)(x >> 16);
}

__device__ __forceinline__ void gload_lds16(const unsigned short* g, unsigned short* l) {
    __builtin_amdgcn_global_load_lds(
        (const __attribute__((address_space(1))) unsigned int*)g,
        (__attribute__((address_space(3))) unsigned int*)l, 16, 0, 0);
}

// ---------------------------------------------------------------------------
// f32 -> bf16 convert, grid-stride, float4 in / ushort4 out
// ---------------------------------------------------------------------------
__global__ __launch_bounds__(256) void cvt_bf16(const float* __restrict__ s,
                                                unsigned short* __restrict__ d, int n) {
    const int stride = gridDim.x * blockDim.x * 4;
    for (int i = (blockIdx.x * blockDim.x + threadIdx.x) * 4; i < n; i += stride) {
        const float4 v = *reinterpret_cast<const float4*>(s + i);
        ushort4 o;
        o.x = f2bf(v.x); o.y = f2bf(v.y); o.z = f2bf(v.z); o.w = f2bf(v.w);
        *reinterpret_cast<ushort4*>(d + i) = o;
    }
}

// 4 weight matrices (512x512 each) -> contiguous bf16, one launch
__global__ __launch_bounds__(256) void cvt_w4(const float* __restrict__ w0,
                                              const float* __restrict__ w1,
                                              const float* __restrict__ w2,
                                              const float* __restrict__ w3,
                                              unsigned short* __restrict__ d) {
    const float* srcs[4] = {w0, w1, w2, w3};
    const float* s = srcs[blockIdx.y];
    unsigned short* dst = d + (size_t)blockIdx.y * (SIZE_D * SIZE_D);
    const int n = SIZE_D * SIZE_D;
    const int stride = gridDim.x * blockDim.x * 4;
    for (int i = (blockIdx.x * blockDim.x + threadIdx.x) * 4; i < n; i += stride) {
        const float4 v = *reinterpret_cast<const float4*>(s + i);
        ushort4 o;
        o.x = f2bf(v.x); o.y = f2bf(v.y); o.z = f2bf(v.z); o.w = f2bf(v.w);
        *reinterpret_cast<ushort4*>(dst + i) = o;
    }
}

// ---------------------------------------------------------------------------
// MFMA GEMM (unchanged from round 3): 128x128 tile, BK=64, 4 waves,
// global_load_lds(16B) staging w/ swizzle. EPI 0 f32, 1 bf16 head-major, 2 relu+res.
// ---------------------------------------------------------------------------
template <int EPI>
__global__ __launch_bounds__(256, 2) void gemm_mfma(const unsigned short* __restrict__ A,
                                                    const unsigned short* __restrict__ W,
                                                    const float* __restrict__ bias,
                                                    const float* __restrict__ R,
                                                    float* __restrict__ C,
                                                    unsigned short* __restrict__ Hd) {
    __shared__ __align__(16) unsigned short Ad[2][128 * 64];
    __shared__ __align__(16) unsigned short Bd[2][128 * 64];

    const int tid  = threadIdx.x;
    const int wv   = tid >> 6;
    const int lane = tid & 63;
    const int bm   = blockIdx.x * 128;
    const int bn   = blockIdx.y * 128;
    const int wr   = wv >> 1;
    const int wc   = wv & 1;

    auto stage = [&](int buf, int t) {
        const int k0 = t * 64;
#pragma unroll
        for (int i = 0; i < 4; ++i) {
            const int o     = (wv * 32 + i * 8) * 128 + lane * 16;
            const int row   = o >> 7;
            const int inrow = (o & 127) ^ ((row & 7) << 4);
            const int col   = inrow >> 1;
            gload_lds16(A + (size_t)(bm + row) * SIZE_D + k0 + col, &Ad[buf][o >> 1]);
            gload_lds16(W + (size_t)(bn + row) * SIZE_D + k0 + col, &Bd[buf][o >> 1]);
        }
    };

    f32x4 acc[4][4];
#pragma unroll
    for (int mt = 0; mt < 4; ++mt)
#pragma unroll
        for (int nt = 0; nt < 4; ++nt) acc[mt][nt] = (f32x4){0.f, 0.f, 0.f, 0.f};

    stage(0, 0);
    __syncthreads();
    int cur = 0;

    for (int t = 0; t < 8; ++t) {
        if (t < 7) stage(cur ^ 1, t + 1);

        bf16x8 af[2][4], bfr[2][4];
#pragma unroll
        for (int kc = 0; kc < 2; ++kc) {
#pragma unroll
            for (int mt = 0; mt < 4; ++mt) {
                const int r = wr * 64 + mt * 16 + (lane & 15);
                int byte = r * 128 + kc * 64 + (lane >> 4) * 16;
                byte ^= (r & 7) << 4;
                af[kc][mt] = *reinterpret_cast<const bf16x8*>(
                    reinterpret_cast<const char*>(&Ad[cur][0]) + byte);
            }
#pragma unroll
            for (int nt = 0; nt < 4; ++nt) {
                const int r = wc * 64 + nt * 16 + (lane & 15);
                int byte = r * 128 + kc * 64 + (lane >> 4) * 16;
                byte ^= (r & 7) << 4;
                bfr[kc][nt] = *reinterpret_cast<const bf16x8*>(
                    reinterpret_cast<const char*>(&Bd[cur][0]) + byte);
            }
        }
#pragma unroll
        for (int kc = 0; kc < 2; ++kc)
#pragma unroll
            for (int mt = 0; mt < 4; ++mt)
#pragma unroll
                for (int nt = 0; nt < 4; ++nt)
                    acc[mt][nt] = __builtin_amdgcn_mfma_f32_16x16x32_bf16(
                        af[kc][mt], bfr[kc][nt], acc[mt][nt], 0, 0, 0);

        __syncthreads();
        cur ^= 1;
    }

#pragma unroll
    for (int nt = 0; nt < 4; ++nt) {
        const int col  = bn + wc * 64 + nt * 16 + (lane & 15);
        const float bc = bias[col];
#pragma unroll
        for (int mt = 0; mt < 4; ++mt) {
            const int row0 = bm + wr * 64 + mt * 16 + (lane >> 4) * 4;
#pragma unroll
            for (int r = 0; r < 4; ++r) {
                const int row = row0 + r;
                float z = acc[mt][nt][r] + bc;
                if (EPI == 2) {
                    z = R[(size_t)row * SIZE_D + col] + fmaxf(z, 0.0f);
                }
                if (EPI == 1) {
                    const int b_ = row >> 9, l = row & 511;
                    const int h  = col >> 6, dd = col & 63;
                    Hd[(((size_t)b_ * HEADS + h) * SEQ + l) * HDIM + dd] = f2bf(z);
                } else {
                    C[(size_t)row * SIZE_D + col] = z;
                }
            }
        }
    }
}

// ---------------------------------------------------------------------------
// MFMA attention, one (b,h) per block, 8 waves x 64 Q-rows.
// Swapped QK^T: sacc = mfma(K,Q) -> lane holds col=q, rows=4 consecutive k.
// W transform packs 4 bf16 (consecutive k) into one ds_write_b64 to P[q][k]
// row-major (XOR-swizzled). PV reads P rows as A-frags (b128, same swizzle).
// ---------------------------------------------------------------------------
__global__ __launch_bounds__(512, 2) void attn_mfma(float* __restrict__ q,
                                                    const unsigned short* __restrict__ Kh,
                                                    const unsigned short* __restrict__ Vh) {
    __shared__ __align__(16) unsigned short VtL[64 * 512];   // Vt[d][kv], swizzled
    __shared__ __align__(16) unsigned short WL[8][64 * 64];  // per-wave P[q][k] scratch

    const int tid  = threadIdx.x;
    const int wv   = tid >> 6;
    const int lane = tid & 63;
    const int bh   = blockIdx.x;
    const int b    = bh >> 3;
    const int h    = bh & 7;

    const unsigned short* Kb = Kh + (size_t)bh * (SEQ * HDIM);
    const unsigned short* Vb = Vh + (size_t)bh * (SEQ * HDIM);
    float* qb = q + (size_t)b * (SEQ * SIZE_D) + h * HDIM;

    // ---- stage V transposed into VtL (bounce tile overlays WL) ----
    unsigned short* Tb = &WL[0][0];    // [64][66] ushort bounce
    for (int c = 0; c < 8; ++c) {
        {
            const int kv = tid >> 3;
            const int d8 = (tid & 7) * 8;
            u32x4 rv = *reinterpret_cast<const u32x4*>(Vb + (size_t)(c * 64 + kv) * HDIM + d8);
            const unsigned short* rs = reinterpret_cast<const unsigned short*>(&rv);
            __syncthreads();
            unsigned short* dst = &Tb[kv * 66 + d8];
#pragma unroll
            for (int j = 0; j < 8; ++j) dst[j] = rs[j];
        }
        __syncthreads();
        {
            const int d  = tid >> 3;
            const int k8 = (tid & 7) * 8;
            unsigned short tmp[8];
#pragma unroll
            for (int j = 0; j < 8; ++j) tmp[j] = Tb[(k8 + j) * 66 + d];
            int byte = d * 1024 + (c * 64 + k8) * 2;
            byte ^= (d & 7) << 4;
            *reinterpret_cast<u32x4*>(reinterpret_cast<char*>(VtL) + byte) =
                *reinterpret_cast<const u32x4*>(tmp);
        }
    }
    __syncthreads();

    // ---- per-wave Q fragments, SCALE pre-folded ----
    const int m0 = wv * 64;
    bf16x8 qf[4][2];
#pragma unroll
    for (int mt = 0; mt < 4; ++mt)
#pragma unroll
        for (int kc = 0; kc < 2; ++kc) {
            const int m = m0 + mt * 16 + (lane & 15);
            const int d = kc * 32 + (lane >> 4) * 8;
            const float* src = qb + (size_t)m * SIZE_D + d;
            const float4 a0 = *reinterpret_cast<const float4*>(src);
            const float4 a1 = *reinterpret_cast<const float4*>(src + 4);
            union { bf16x8 v; unsigned short s[8]; } u;
            u.s[0] = f2bf(a0.x * SCALE_F); u.s[1] = f2bf(a0.y * SCALE_F);
            u.s[2] = f2bf(a0.z * SCALE_F); u.s[3] = f2bf(a0.w * SCALE_F);
            u.s[4] = f2bf(a1.x * SCALE_F); u.s[5] = f2bf(a1.y * SCALE_F);
            u.s[6] = f2bf(a1.z * SCALE_F); u.s[7] = f2bf(a1.w * SCALE_F);
            qf[mt][kc] = u.v;
        }

    unsigned short* myW = &WL[wv][0];
    f32x4 oacc[4][4];
    float esum[4] = {0.f, 0.f, 0.f, 0.f};
#pragma unroll
    for (int mt = 0; mt < 4; ++mt)
#pragma unroll
        for (int x = 0; x < 4; ++x) oacc[mt][x] = (f32x4){0.f, 0.f, 0.f, 0.f};

    for (int t = 0; t < 8; ++t) {
        const int kv0 = t * 64;
        f32x4 sacc[4][4];   // [nt = k-tile][mt = q-tile]
#pragma unroll
        for (int nt = 0; nt < 4; ++nt)
#pragma unroll
            for (int mt = 0; mt < 4; ++mt) sacc[nt][mt] = (f32x4){0.f, 0.f, 0.f, 0.f};

#pragma unroll
        for (int kc = 0; kc < 2; ++kc) {
            bf16x8 kf[4];
#pragma unroll
            for (int nt = 0; nt < 4; ++nt) {
                const int kv = kv0 + nt * 16 + (lane & 15);
                const int d  = kc * 32 + (lane >> 4) * 8;
                union { u32x4 u; bf16x8 v; } cv;
                cv.u = *reinterpret_cast<const u32x4*>(Kb + (size_t)kv * HDIM + d);
                kf[nt] = cv.v;
            }
#pragma unroll
            for (int nt = 0; nt < 4; ++nt)
#pragma unroll
                for (int mt = 0; mt < 4; ++mt)
                    sacc[nt][mt] = __builtin_amdgcn_mfma_f32_16x16x32_bf16(
                        kf[nt], qf[mt][kc], sacc[nt][mt], 0, 0, 0);
        }

        // transform: w = tanh(s)*exp(sqrt(s^2+.01)); pack 4 consecutive-k bf16 -> b64
#pragma unroll
        for (int nt = 0; nt < 4; ++nt)
#pragma unroll
            for (int mt = 0; mt < 4; ++mt) {
                float w[4];
#pragma unroll
                for (int r = 0; r < 4; ++r) {
                    const float s  = sacc[nt][mt][r];
                    const float tt = __expf(fminf(s + s, 50.0f));       // e^{2s}
                    const float u  = __builtin_amdgcn_sqrtf(fmaf(s, s, 0.01f));
                    const float ee = __expf(u);
                    esum[mt] += ee;
                    w[r] = (tt - 1.0f) * ee * __builtin_amdgcn_rcpf(tt + 1.0f);
                }
                uint2 pk;   // truncating f32->bf16 pack (error < 0.4%, fine here)
                pk.x = (__float_as_uint(w[1]) & 0xffff0000u) | (__float_as_uint(w[0]) >> 16);
                pk.y = (__float_as_uint(w[3]) & 0xffff0000u) | (__float_as_uint(w[2]) >> 16);
                int byte = (mt * 16 + (lane & 15)) * 128 + nt * 32 + (lane >> 4) * 8;
                byte ^= (lane & 7) << 4;
                *reinterpret_cast<uint2*>(reinterpret_cast<char*>(myW) + byte) = pk;
            }

        // PV: O += P * V
#pragma unroll
        for (int kc2 = 0; kc2 < 2; ++kc2) {
            bf16x8 wf[4], vf[4];
#pragma unroll
            for (int mt = 0; mt < 4; ++mt) {
                const int row = mt * 16 + (lane & 15);
                int byte = row * 128 + kc2 * 64 + (lane >> 4) * 16;
                byte ^= (row & 7) << 4;
                union { u32x4 u; bf16x8 v; } cv;
                cv.u = *reinterpret_cast<const u32x4*>(reinterpret_cast<char*>(myW) + byte);
                wf[mt] = cv.v;
            }
#pragma unroll
            for (int dt = 0; dt < 4; ++dt) {
                const int d = dt * 16 + (lane & 15);
                int byte = d * 1024 + (kv0 + kc2 * 32 + (lane >> 4) * 8) * 2;
                byte ^= (d & 7) << 4;
                union { u32x4 u; bf16x8 v; } cv;
                cv.u = *reinterpret_cast<const u32x4*>(reinterpret_cast<char*>(VtL) + byte);
                vf[dt] = cv.v;
            }
#pragma unroll
            for (int mt = 0; mt < 4; ++mt)
#pragma unroll
                for (int dt = 0; dt < 4; ++dt)
                    oacc[mt][dt] = __builtin_amdgcn_mfma_f32_16x16x32_bf16(
                        wf[mt], vf[dt], oacc[mt][dt], 0, 0, 0);
        }
    }

    // ---- epilogue: reduce esum across lane groups, normalize, residual ----
    float rden[4];
#pragma unroll
    for (int mt = 0; mt < 4; ++mt) {
        float e = esum[mt];
        e += __shfl_xor(e, 16);
        e += __shfl_xor(e, 32);
        rden[mt] = __builtin_amdgcn_rcpf(e);
    }
    float rr_[4][4];
#pragma unroll
    for (int mt = 0; mt < 4; ++mt)
#pragma unroll
        for (int r = 0; r < 4; ++r)
            rr_[mt][r] = __shfl(rden[mt], (lane >> 4) * 4 + r);

#pragma unroll
    for (int mt = 0; mt < 4; ++mt)
#pragma unroll
        for (int dt = 0; dt < 4; ++dt)
#pragma unroll
            for (int r = 0; r < 4; ++r) {
                const int m = m0 + mt * 16 + (lane >> 4) * 4 + r;
                const int d = dt * 16 + (lane & 15);
                float* p = qb + (size_t)m * SIZE_D + d;
                *p = *p + oacc[mt][dt][r] * rr_[mt][r];
            }
}

// ---------------------------------------------------------------------------
// Row LayerNorm over 512 elems; optional extra bf16 output.
// ---------------------------------------------------------------------------
template <int BF16OUT>
__global__ __launch_bounds__(256) void ln_kernel(const float* __restrict__ in,
                                                 const float* __restrict__ w,
                                                 const float* __restrict__ b,
                                                 float* __restrict__ out,
                                                 unsigned short* __restrict__ outb) {
    const int row = blockIdx.x;
    const int tid = threadIdx.x;
    const float2 x = *reinterpret_cast<const float2*>(&in[(size_t)row * SIZE_D + tid * 2]);

    float s  = x.x + x.y;
    float sq = x.x * x.x + x.y * x.y;
#pragma unroll
    for (int off = 32; off > 0; off >>= 1) {
        s  += __shfl_xor(s, off);
        sq += __shfl_xor(sq, off);
    }
    __shared__ float rs[4], rq[4];
    const int wv = tid >> 6;
    if ((tid & 63) == 0) { rs[wv] = s; rq[wv] = sq; }
    __syncthreads();
    s  = rs[0] + rs[1] + rs[2] + rs[3];
    sq = rq[0] + rq[1] + rq[2] + rq[3];

    const float mu  = s * (1.0f / SIZE_D);
    const float var = sq * (1.0f / SIZE_D) - mu * mu;
    const float rr  = rsqrtf(var + 1e-5f);

    const float2 wv2 = *reinterpret_cast<const float2*>(&w[tid * 2]);
    const float2 bv2 = *reinterpret_cast<const float2*>(&b[tid * 2]);
    float2 o;
    o.x = (x.x - mu) * rr * wv2.x + bv2.x;
    o.y = (x.y - mu) * rr * wv2.y + bv2.y;
    *reinterpret_cast<float2*>(&out[(size_t)row * SIZE_D + tid * 2]) = o;
    if (BF16OUT) {
        ushort2 ob;
        ob.x = f2bf(o.x); ob.y = f2bf(o.y);
        *reinterpret_cast<ushort2*>(&outb[(size_t)row * SIZE_D + tid * 2]) = ob;
    }
}

// ---------------------------------------------------------------------------
extern "C" void kernel_launch(void* const* d_in, const int* in_sizes, int n_in,
                              void* d_out, int out_size, void* d_ws, size_t ws_size,
                              hipStream_t stream) {
    const float* query = (const float*)d_in[0];
    const float* keyv  = (const float*)d_in[1];
    const float* Wq    = (const float*)d_in[2];
    const float* bq    = (const float*)d_in[3];
    const float* Wk    = (const float*)d_in[4];
    const float* bk    = (const float*)d_in[5];
    const float* Wv    = (const float*)d_in[6];
    const float* bv    = (const float*)d_in[7];
    const float* Wo    = (const float*)d_in[8];
    const float* bo    = (const float*)d_in[9];
    const float* ln0w  = (const float*)d_in[10];
    const float* ln0b  = (const float*)d_in[11];
    const float* ln1w  = (const float*)d_in[12];
    const float* ln1b  = (const float*)d_in[13];
    float* out = (float*)d_out;

    // workspace (96 MB):
    //   [ 0,32) qbuf f32
    //   [32,48) Kh bf16   \ obuf f32 aliases [32,64) after attention
    //   [48,64) Vh bf16   /
    //   [64,80) Qbf bf16 (query)
    //   [80,96) KVbf bf16 (key_value) -> reused as Xbf (ln0 bf16) later
    // d_out: first 2 MB = bf16 weights (dead before LN1 writes out)
    char* ws = (char*)d_ws;
    float*          qbuf = (float*)ws;
    unsigned short* Kh   = (unsigned short*)(ws + ((size_t)32 << 20));
    unsigned short* Vh   = (unsigned short*)(ws + ((size_t)48 << 20));
    float*          obuf = (float*)(ws + ((size_t)32 << 20));
    unsigned short* Qbf  = (unsigned short*)(ws + ((size_t)64 << 20));
    unsigned short* KVbf = (unsigned short*)(ws + ((size_t)80 << 20));
    unsigned short* Xbf  = KVbf;

    unsigned short* Wbf = (unsigned short*)d_out;
    unsigned short* WqB = Wbf;
    unsigned short* WkB = Wbf + 262144;
    unsigned short* WvB = Wbf + 524288;
    unsigned short* WoB = Wbf + 786432;

    const int NACT = NROWS * SIZE_D;   // 8,388,608

    cvt_bf16<<<2048, 256, 0, stream>>>(query, Qbf, NACT);
    cvt_bf16<<<2048, 256, 0, stream>>>(keyv, KVbf, NACT);
    cvt_w4<<<dim3(64, 4), 256, 0, stream>>>(Wq, Wk, Wv, Wo, Wbf);

    const dim3 gg(NROWS / 128, SIZE_D / 128);   // (128, 4)

    gemm_mfma<0><<<gg, 256, 0, stream>>>(Qbf,  WqB, bq, nullptr, qbuf, nullptr);
    gemm_mfma<1><<<gg, 256, 0, stream>>>(KVbf, WkB, bk, nullptr, nullptr, Kh);
    gemm_mfma<1><<<gg, 256, 0, stream>>>(KVbf, WvB, bv, nullptr, nullptr, Vh);

    attn_mfma<<<BATCH * HEADS, 512, 0, stream>>>(qbuf, Kh, Vh);

    ln_kernel<1><<<NROWS, 256, 0, stream>>>(qbuf, ln0w, ln0b, qbuf, Xbf);
    gemm_mfma<2><<<gg, 256, 0, stream>>>(Xbf, WoB, bo, qbuf, obuf, nullptr);
    ln_kernel<0><<<NROWS, 256, 0, stream>>>(obuf, ln1w, ln1b, out, nullptr);
}

// Round 5
// 171.699 us; speedup vs baseline: 9.7666x; 1.0529x over previous
//
#include <hip/hip_runtime.h>

#define SIZE_D 512
#define HEADS  8
#define HDIM   64
#define BATCH  32
#define SEQ    512
#define SCALE_F 0.125f   // 1/sqrt(64)
#define NROWS  (BATCH * SEQ)   // 16384

typedef __attribute__((ext_vector_type(8))) short bf16x8;
typedef __attribute__((ext_vector_type(4))) float f32x4;
typedef __attribute__((ext_vector_type(4))) unsigned int u32x4;

__device__ __forceinline__ unsigned short f2bf(float f) {
    union { float f; unsigned int u; } c{f};
    unsigned int x = c.u;
    x += 0x7fffu + ((x >> 16) & 1u);   // RNE
    return (unsigned short)(x >> 16);
}
__device__ __forceinline__ float bf2f(unsigned short u) {
    union { unsigned int i; float f; } c;
    c.i = (unsigned int)u << 16;
    return c.f;
}
__device__ __forceinline__ void gload_lds16(const unsigned short* g, unsigned short* l) {
    __builtin_amdgcn_global_load_lds(
        (const __attribute__((address_space(1))) unsigned int*)g,
        (__attribute__((address_space(3))) unsigned int*)l, 16, 0, 0);
}

// ---------------------------------------------------------------------------
// activations f32 -> bf16 (query / key_value picked by blockIdx.y)
// ---------------------------------------------------------------------------
__global__ __launch_bounds__(256) void cvt_act(const float* __restrict__ q,
                                               const float* __restrict__ kv,
                                               unsigned short* __restrict__ dq,
                                               unsigned short* __restrict__ dkv) {
    const float* s = blockIdx.y ? kv : q;
    unsigned short* d = blockIdx.y ? dkv : dq;
    const int n = NROWS * SIZE_D;
    const int stride = gridDim.x * blockDim.x * 4;
    for (int i = (blockIdx.x * blockDim.x + threadIdx.x) * 4; i < n; i += stride) {
        const float4 v = *reinterpret_cast<const float4*>(s + i);
        ushort4 o;
        o.x = f2bf(v.x); o.y = f2bf(v.y); o.z = f2bf(v.z); o.w = f2bf(v.w);
        *reinterpret_cast<ushort4*>(d + i) = o;
    }
}

// 4 weight matrices (512x512) -> contiguous bf16
__global__ __launch_bounds__(256) void cvt_w4(const float* __restrict__ w0,
                                              const float* __restrict__ w1,
                                              const float* __restrict__ w2,
                                              const float* __restrict__ w3,
                                              unsigned short* __restrict__ d) {
    const float* srcs[4] = {w0, w1, w2, w3};
    const float* s = srcs[blockIdx.y];
    unsigned short* dst = d + (size_t)blockIdx.y * (SIZE_D * SIZE_D);
    const int n = SIZE_D * SIZE_D;
    const int stride = gridDim.x * blockDim.x * 4;
    for (int i = (blockIdx.x * blockDim.x + threadIdx.x) * 4; i < n; i += stride) {
        const float4 v = *reinterpret_cast<const float4*>(s + i);
        ushort4 o;
        o.x = f2bf(v.x); o.y = f2bf(v.y); o.z = f2bf(v.z); o.w = f2bf(v.w);
        *reinterpret_cast<ushort4*>(dst + i) = o;
    }
}

// ---------------------------------------------------------------------------
// Projection GEMM: z = A @ W^T + bias. 128x128 tile, BK=64, 4 waves.
// KV=0 (grid y=4):  D0 = Qh[b,h,l,d] = bf16(z)                (unscaled)
// KV=1 (grid y=8):  cols<512 -> D0 = Kh[b,h,l,d] = bf16(z*SCALE)
//                   cols>=512 -> D1 = Vt[b,h,d,kv] = bf16(z)  (transposed, 8B packs)
// ---------------------------------------------------------------------------
template <int KV>
__global__ __launch_bounds__(256, 2) void gemm_proj(const unsigned short* __restrict__ A,
                                                    const unsigned short* __restrict__ W,
                                                    const float* __restrict__ bias0,
                                                    const float* __restrict__ bias1,
                                                    unsigned short* __restrict__ D0,
                                                    unsigned short* __restrict__ D1) {
    __shared__ __align__(16) unsigned short Ad[2][128 * 64];
    __shared__ __align__(16) unsigned short Bd[2][128 * 64];

    const int tid  = threadIdx.x;
    const int wv   = tid >> 6;
    const int lane = tid & 63;
    const int bm   = blockIdx.x * 128;
    const int bn   = blockIdx.y * 128;
    const int wr   = wv >> 1;
    const int wc   = wv & 1;

    auto stage = [&](int buf, int t) {
        const int k0 = t * 64;
#pragma unroll
        for (int i = 0; i < 4; ++i) {
            const int o     = (wv * 32 + i * 8) * 128 + lane * 16;
            const int row   = o >> 7;
            const int inrow = (o & 127) ^ ((row & 7) << 4);
            const int col   = inrow >> 1;
            gload_lds16(A + (size_t)(bm + row) * SIZE_D + k0 + col, &Ad[buf][o >> 1]);
            gload_lds16(W + (size_t)(bn + row) * SIZE_D + k0 + col, &Bd[buf][o >> 1]);
        }
    };

    f32x4 acc[4][4];
#pragma unroll
    for (int mt = 0; mt < 4; ++mt)
#pragma unroll
        for (int nt = 0; nt < 4; ++nt) acc[mt][nt] = (f32x4){0.f, 0.f, 0.f, 0.f};

    stage(0, 0);
    __syncthreads();
    int cur = 0;

    for (int t = 0; t < 8; ++t) {
        if (t < 7) stage(cur ^ 1, t + 1);

        bf16x8 af[2][4], bfr[2][4];
#pragma unroll
        for (int kc = 0; kc < 2; ++kc) {
#pragma unroll
            for (int mt = 0; mt < 4; ++mt) {
                const int r = wr * 64 + mt * 16 + (lane & 15);
                int byte = r * 128 + kc * 64 + (lane >> 4) * 16;
                byte ^= (r & 7) << 4;
                af[kc][mt] = *reinterpret_cast<const bf16x8*>(
                    reinterpret_cast<const char*>(&Ad[cur][0]) + byte);
            }
#pragma unroll
            for (int nt = 0; nt < 4; ++nt) {
                const int r = wc * 64 + nt * 16 + (lane & 15);
                int byte = r * 128 + kc * 64 + (lane >> 4) * 16;
                byte ^= (r & 7) << 4;
                bfr[kc][nt] = *reinterpret_cast<const bf16x8*>(
                    reinterpret_cast<const char*>(&Bd[cur][0]) + byte);
            }
        }
#pragma unroll
        for (int kc = 0; kc < 2; ++kc)
#pragma unroll
            for (int mt = 0; mt < 4; ++mt)
#pragma unroll
                for (int nt = 0; nt < 4; ++nt)
                    acc[mt][nt] = __builtin_amdgcn_mfma_f32_16x16x32_bf16(
                        af[kc][mt], bfr[kc][nt], acc[mt][nt], 0, 0, 0);

        __syncthreads();
        cur ^= 1;
    }

    if (KV == 0 || bn < 512) {
        // head-major bf16 (K additionally pre-scaled by 1/sqrt(hd))
#pragma unroll
        for (int nt = 0; nt < 4; ++nt) {
            const int col = bn + wc * 64 + nt * 16 + (lane & 15);
            const float bc = bias0[col];
            const int h = (col >> 6) & 7, dd = col & 63;
#pragma unroll
            for (int mt = 0; mt < 4; ++mt) {
                const int row0 = bm + wr * 64 + mt * 16 + (lane >> 4) * 4;
#pragma unroll
                for (int r = 0; r < 4; ++r) {
                    const int row = row0 + r;
                    const int b_ = row >> 9, l = row & 511;
                    float z = acc[mt][nt][r] + bc;
                    if (KV) z *= SCALE_F;
                    D0[(((size_t)b_ * HEADS + h) * SEQ + l) * HDIM + dd] = f2bf(z);
                }
            }
        }
    } else {
        // V: transposed Vt[b,h,d,kv], 4 consecutive kv packed per 8B store
#pragma unroll
        for (int nt = 0; nt < 4; ++nt) {
            const int c2 = bn + wc * 64 + nt * 16 + (lane & 15) - 512;
            const float bc = bias1[c2];
            const int hV = c2 >> 6, dV = c2 & 63;
#pragma unroll
            for (int mt = 0; mt < 4; ++mt) {
                const int row0 = bm + wr * 64 + mt * 16 + (lane >> 4) * 4;
                const int b_ = row0 >> 9, kv = row0 & 511;
                ushort4 pk;
                pk.x = f2bf(acc[mt][nt][0] + bc);
                pk.y = f2bf(acc[mt][nt][1] + bc);
                pk.z = f2bf(acc[mt][nt][2] + bc);
                pk.w = f2bf(acc[mt][nt][3] + bc);
                *reinterpret_cast<ushort4*>(
                    &D1[(((size_t)b_ * HEADS + hV) * HDIM + dV) * SEQ + kv]) = pk;
            }
        }
    }
}

// ---------------------------------------------------------------------------
// MFMA attention. Block = (bh, half): 256 thr = 4 waves x 64 q-rows.
// Q,K from bf16 head-major global; V from transposed global Vt[b,h,d,kv].
// LDS = per-wave P scratch only (32KB) -> multi-block/CU.
// 3-transcendental transform: e^u = e^{|s|} * poly(u-|s|).
// Writes O = q + PV/esum  (f32, [b,l,512] layout).
// ---------------------------------------------------------------------------
__global__ __launch_bounds__(256, 2) void attn_mfma(const unsigned short* __restrict__ Qh,
                                                    const unsigned short* __restrict__ Kh,
                                                    const unsigned short* __restrict__ Vt,
                                                    float* __restrict__ outq) {
    __shared__ __align__(16) unsigned short WL[4][64 * 64];   // per-wave P[q][k]

    const int tid  = threadIdx.x;
    const int wv   = tid >> 6;
    const int lane = tid & 63;
    const int bh   = blockIdx.x;
    const int half = blockIdx.y;
    const int b    = bh >> 3;
    const int h    = bh & 7;

    const unsigned short* Qb = Qh + (size_t)bh * (SEQ * HDIM);
    const unsigned short* Kb = Kh + (size_t)bh * (SEQ * HDIM);
    const unsigned short* Vb = Vt + (size_t)bh * (HDIM * SEQ);

    const int m0 = half * 256 + wv * 64;

    // Q fragments (A-layout: row=lane&15, k=8*(lane>>4)+j), bf16 direct
    bf16x8 qf[4][2];
#pragma unroll
    for (int mt = 0; mt < 4; ++mt)
#pragma unroll
        for (int kc = 0; kc < 2; ++kc) {
            const int m = m0 + mt * 16 + (lane & 15);
            union { u32x4 u; bf16x8 v; } cv;
            cv.u = *reinterpret_cast<const u32x4*>(
                Qb + (size_t)m * HDIM + kc * 32 + (lane >> 4) * 8);
            qf[mt][kc] = cv.v;
        }

    unsigned short* myW = &WL[wv][0];
    f32x4 oacc[4][4];
    float esum[4] = {0.f, 0.f, 0.f, 0.f};
#pragma unroll
    for (int mt = 0; mt < 4; ++mt)
#pragma unroll
        for (int x = 0; x < 4; ++x) oacc[mt][x] = (f32x4){0.f, 0.f, 0.f, 0.f};

    for (int t = 0; t < 8; ++t) {
        const int kv0 = t * 64;
        f32x4 sacc[4][4];   // [nt=k-tile][mt=q-tile]
#pragma unroll
        for (int nt = 0; nt < 4; ++nt)
#pragma unroll
            for (int mt = 0; mt < 4; ++mt) sacc[nt][mt] = (f32x4){0.f, 0.f, 0.f, 0.f};

#pragma unroll
        for (int kc = 0; kc < 2; ++kc) {
            bf16x8 kf[4];
#pragma unroll
            for (int nt = 0; nt < 4; ++nt) {
                const int kv = kv0 + nt * 16 + (lane & 15);
                union { u32x4 u; bf16x8 v; } cv;
                cv.u = *reinterpret_cast<const u32x4*>(
                    Kb + (size_t)kv * HDIM + kc * 32 + (lane >> 4) * 8);
                kf[nt] = cv.v;
            }
#pragma unroll
            for (int nt = 0; nt < 4; ++nt)
#pragma unroll
                for (int mt = 0; mt < 4; ++mt)
                    sacc[nt][mt] = __builtin_amdgcn_mfma_f32_16x16x32_bf16(
                        kf[nt], qf[mt][kc], sacc[nt][mt], 0, 0, 0);
        }

        // transform: w = tanh(s)*e^u, u = sqrt(s^2+0.01)
        // 3 trans ops: exp(|s|), sqrt, rcp;  e^u = e^{|s|}*poly(u-|s|), d<=0.1
#pragma unroll
        for (int nt = 0; nt < 4; ++nt)
#pragma unroll
            for (int mt = 0; mt < 4; ++mt) {
                float w[4];
#pragma unroll
                for (int r = 0; r < 4; ++r) {
                    const float s  = sacc[nt][mt][r];
                    const float a  = fminf(fabsf(s), 30.0f);
                    const float tt = __expf(a);
                    const float t2 = tt * tt;
                    const float u  = __builtin_amdgcn_sqrtf(fmaf(s, s, 0.01f));
                    const float dl = u - a;
                    const float ed = fmaf(dl, fmaf(dl, fmaf(dl, 0.16666667f, 0.5f), 1.0f), 1.0f);
                    const float eu = tt * ed;
                    esum[mt] += eu;
                    const float th = (t2 - 1.0f) * __builtin_amdgcn_rcpf(t2 + 1.0f);
                    w[r] = __builtin_copysignf(th * eu, s);
                }
                uint2 pk;   // truncating bf16 pack
                pk.x = (__float_as_uint(w[1]) & 0xffff0000u) | (__float_as_uint(w[0]) >> 16);
                pk.y = (__float_as_uint(w[3]) & 0xffff0000u) | (__float_as_uint(w[2]) >> 16);
                int byte = (mt * 16 + (lane & 15)) * 128 + nt * 32 + (lane >> 4) * 8;
                byte ^= (lane & 7) << 4;
                *reinterpret_cast<uint2*>(reinterpret_cast<char*>(myW) + byte) = pk;
            }

        // PV: O += P * V  (P from LDS, V frags from global Vt)
#pragma unroll
        for (int kc2 = 0; kc2 < 2; ++kc2) {
            bf16x8 wf[4], vf[4];
#pragma unroll
            for (int mt = 0; mt < 4; ++mt) {
                const int row = mt * 16 + (lane & 15);
                int byte = row * 128 + kc2 * 64 + (lane >> 4) * 16;
                byte ^= (row & 7) << 4;
                union { u32x4 u; bf16x8 v; } cv;
                cv.u = *reinterpret_cast<const u32x4*>(reinterpret_cast<char*>(myW) + byte);
                wf[mt] = cv.v;
            }
#pragma unroll
            for (int dt = 0; dt < 4; ++dt) {
                const int d = dt * 16 + (lane & 15);
                union { u32x4 u; bf16x8 v; } cv;
                cv.u = *reinterpret_cast<const u32x4*>(
                    Vb + (size_t)d * SEQ + kv0 + kc2 * 32 + (lane >> 4) * 8);
                vf[dt] = cv.v;
            }
#pragma unroll
            for (int mt = 0; mt < 4; ++mt)
#pragma unroll
                for (int dt = 0; dt < 4; ++dt)
                    oacc[mt][dt] = __builtin_amdgcn_mfma_f32_16x16x32_bf16(
                        wf[mt], vf[dt], oacc[mt][dt], 0, 0, 0);
        }
    }

    // epilogue
    float rden[4];
#pragma unroll
    for (int mt = 0; mt < 4; ++mt) {
        float e = esum[mt];
        e += __shfl_xor(e, 16);
        e += __shfl_xor(e, 32);
        rden[mt] = __builtin_amdgcn_rcpf(e);
    }
    float rr_[4][4];
#pragma unroll
    for (int mt = 0; mt < 4; ++mt)
#pragma unroll
        for (int r = 0; r < 4; ++r)
            rr_[mt][r] = __shfl(rden[mt], (lane >> 4) * 4 + r);

#pragma unroll
    for (int mt = 0; mt < 4; ++mt)
#pragma unroll
        for (int dt = 0; dt < 4; ++dt)
#pragma unroll
            for (int r = 0; r < 4; ++r) {
                const int m = m0 + mt * 16 + (lane >> 4) * 4 + r;
                const int d = dt * 16 + (lane & 15);
                const float qv = bf2f(Qb[(size_t)m * HDIM + d]);
                outq[((size_t)b * SEQ + m) * SIZE_D + h * HDIM + d] =
                    qv + oacc[mt][dt][r] * rr_[mt][r];
            }
}

// ---------------------------------------------------------------------------
// LN0: f32 in -> bf16 out only (bf16 serves as both GEMM-A and residual R)
// ---------------------------------------------------------------------------
__global__ __launch_bounds__(256) void ln0_bf16(const float* __restrict__ in,
                                                const float* __restrict__ w,
                                                const float* __restrict__ b,
                                                unsigned short* __restrict__ outb) {
    const int row = blockIdx.x;
    const int tid = threadIdx.x;
    const float2 x = *reinterpret_cast<const float2*>(&in[(size_t)row * SIZE_D + tid * 2]);

    float s  = x.x + x.y;
    float sq = x.x * x.x + x.y * x.y;
#pragma unroll
    for (int off = 32; off > 0; off >>= 1) {
        s  += __shfl_xor(s, off);
        sq += __shfl_xor(sq, off);
    }
    __shared__ float rs[4], rq[4];
    const int wv = tid >> 6;
    if ((tid & 63) == 0) { rs[wv] = s; rq[wv] = sq; }
    __syncthreads();
    s  = rs[0] + rs[1] + rs[2] + rs[3];
    sq = rq[0] + rq[1] + rq[2] + rq[3];

    const float mu  = s * (1.0f / SIZE_D);
    const float var = sq * (1.0f / SIZE_D) - mu * mu;
    const float rr  = rsqrtf(var + 1e-5f);

    const float2 wv2 = *reinterpret_cast<const float2*>(&w[tid * 2]);
    const float2 bv2 = *reinterpret_cast<const float2*>(&b[tid * 2]);
    ushort2 ob;
    ob.x = f2bf((x.x - mu) * rr * wv2.x + bv2.x);
    ob.y = f2bf((x.y - mu) * rr * wv2.y + bv2.y);
    *reinterpret_cast<ushort2*>(&outb[(size_t)row * SIZE_D + tid * 2]) = ob;
}

// ---------------------------------------------------------------------------
// Fused out-proj + ReLU + residual + LN1 -> d_out.
// Block = 64 rows x ALL 512 cols (rows complete -> LN in-block).
// 512 thr = 8 waves; wave w owns cols [w*64, w*64+64). BK=64, dbuf.
// ---------------------------------------------------------------------------
__global__ __launch_bounds__(512, 2) void oproj_ln(const unsigned short* __restrict__ X,
                                                   const unsigned short* __restrict__ W,
                                                   const float* __restrict__ bo,
                                                   const float* __restrict__ g1,
                                                   const float* __restrict__ b1,
                                                   float* __restrict__ out) {
    __shared__ __align__(16) unsigned short Ad[2][64 * 64];    // 16KB
    __shared__ __align__(16) unsigned short Bd[2][512 * 64];   // 128KB
    __shared__ float red[64][8][2];                            // 4KB
    __shared__ float stat[64][2];                              // mu, rstd

    const int tid  = threadIdx.x;
    const int wv   = tid >> 6;
    const int lane = tid & 63;
    const int bm   = blockIdx.x * 64;

    auto stage = [&](int buf, int t) {
        const int k0 = t * 64;
        {
            const int o     = tid * 16;
            const int row   = o >> 7;
            const int inrow = (o & 127) ^ ((row & 7) << 4);
            const int col   = inrow >> 1;
            gload_lds16(X + (size_t)(bm + row) * SIZE_D + k0 + col, &Ad[buf][o >> 1]);
        }
#pragma unroll
        for (int i = 0; i < 8; ++i) {
            const int o     = i * 8192 + tid * 16;
            const int row   = o >> 7;
            const int inrow = (o & 127) ^ ((row & 7) << 4);
            const int col   = inrow >> 1;
            gload_lds16(W + (size_t)row * SIZE_D + k0 + col, &Bd[buf][o >> 1]);
        }
    };

    f32x4 acc[4][4];
#pragma unroll
    for (int mt = 0; mt < 4; ++mt)
#pragma unroll
        for (int nt = 0; nt < 4; ++nt) acc[mt][nt] = (f32x4){0.f, 0.f, 0.f, 0.f};

    stage(0, 0);
    __syncthreads();
    int cur = 0;

    for (int t = 0; t < 8; ++t) {
        if (t < 7) stage(cur ^ 1, t + 1);

        bf16x8 af[2][4], bfr[2][4];
#pragma unroll
        for (int kc = 0; kc < 2; ++kc) {
#pragma unroll
            for (int mt = 0; mt < 4; ++mt) {
                const int r = mt * 16 + (lane & 15);
                int byte = r * 128 + kc * 64 + (lane >> 4) * 16;
                byte ^= (r & 7) << 4;
                af[kc][mt] = *reinterpret_cast<const bf16x8*>(
                    reinterpret_cast<const char*>(&Ad[cur][0]) + byte);
            }
#pragma unroll
            for (int nt = 0; nt < 4; ++nt) {
                const int r = wv * 64 + nt * 16 + (lane & 15);
                int byte = r * 128 + kc * 64 + (lane >> 4) * 16;
                byte ^= (r & 7) << 4;
                bfr[kc][nt] = *reinterpret_cast<const bf16x8*>(
                    reinterpret_cast<const char*>(&Bd[cur][0]) + byte);
            }
        }
#pragma unroll
        for (int kc = 0; kc < 2; ++kc)
#pragma unroll
            for (int mt = 0; mt < 4; ++mt)
#pragma unroll
                for (int nt = 0; nt < 4; ++nt)
                    acc[mt][nt] = __builtin_amdgcn_mfma_f32_16x16x32_bf16(
                        af[kc][mt], bfr[kc][nt], acc[mt][nt], 0, 0, 0);

        __syncthreads();
        cur ^= 1;
    }

    // ---- epilogue pass 1: y = R + relu(z + bo) (overwrite acc) ----
#pragma unroll
    for (int nt = 0; nt < 4; ++nt) {
        const int n  = wv * 64 + nt * 16 + (lane & 15);
        const float bc = bo[n];
#pragma unroll
        for (int mt = 0; mt < 4; ++mt) {
            const int row0 = bm + mt * 16 + (lane >> 4) * 4;
#pragma unroll
            for (int r = 0; r < 4; ++r) {
                const float R = bf2f(X[(size_t)(row0 + r) * SIZE_D + n]);
                acc[mt][nt][r] = R + fmaxf(acc[mt][nt][r] + bc, 0.0f);
            }
        }
    }

    // ---- LN1 row stats: per-lane partials over nt, 16-lane butterfly ----
    float ps[4][4], pq[4][4];
#pragma unroll
    for (int mt = 0; mt < 4; ++mt)
#pragma unroll
        for (int r = 0; r < 4; ++r) {
            float s = 0.f, q = 0.f;
#pragma unroll
            for (int nt = 0; nt < 4; ++nt) {
                const float v = acc[mt][nt][r];
                s += v; q += v * v;
            }
#pragma unroll
            for (int off = 1; off <= 8; off <<= 1) {
                s += __shfl_xor(s, off);
                q += __shfl_xor(q, off);
            }
            ps[mt][r] = s; pq[mt][r] = q;
        }
    {   // each lane writes one row's wave-partial (bijective over 64 rows)
        const int mtw = (lane & 15) >> 2, rw = lane & 3;
        const int rowL = mtw * 16 + (lane >> 4) * 4 + rw;
        red[rowL][wv][0] = ps[mtw][rw];
        red[rowL][wv][1] = pq[mtw][rw];
    }
    __syncthreads();
    if (tid < 64) {
        float s = 0.f, q = 0.f;
#pragma unroll
        for (int w8 = 0; w8 < 8; ++w8) { s += red[tid][w8][0]; q += red[tid][w8][1]; }
        const float mu  = s * (1.0f / SIZE_D);
        const float var = q * (1.0f / SIZE_D) - mu * mu;
        stat[tid][0] = mu;
        stat[tid][1] = rsqrtf(var + 1e-5f);
    }
    __syncthreads();

    // ---- normalize + write ----
#pragma unroll
    for (int nt = 0; nt < 4; ++nt) {
        const int n = wv * 64 + nt * 16 + (lane & 15);
        const float g = g1[n], bb = b1[n];
#pragma unroll
        for (int mt = 0; mt < 4; ++mt) {
#pragma unroll
            for (int r = 0; r < 4; ++r) {
                const int rowL = mt * 16 + (lane >> 4) * 4 + r;
                const float y = (acc[mt][nt][r] - stat[rowL][0]) * stat[rowL][1];
                out[(size_t)(bm + rowL) * SIZE_D + n] = y * g + bb;
            }
        }
    }
}

// ---------------------------------------------------------------------------
extern "C" void kernel_launch(void* const* d_in, const int* in_sizes, int n_in,
                              void* d_out, int out_size, void* d_ws, size_t ws_size,
                              hipStream_t stream) {
    const float* query = (const float*)d_in[0];
    const float* keyv  = (const float*)d_in[1];
    const float* Wq    = (const float*)d_in[2];
    const float* bq    = (const float*)d_in[3];
    const float* Wk    = (const float*)d_in[4];
    const float* bk    = (const float*)d_in[5];
    const float* Wv    = (const float*)d_in[6];
    const float* bv    = (const float*)d_in[7];
    const float* Wo    = (const float*)d_in[8];
    const float* bo    = (const float*)d_in[9];
    const float* ln0w  = (const float*)d_in[10];
    const float* ln0b  = (const float*)d_in[11];
    const float* ln1w  = (const float*)d_in[12];
    const float* ln1b  = (const float*)d_in[13];
    float* out = (float*)d_out;

    // workspace layout (82 MB used):
    //   [ 0,16) Qbf bf16      (phase 1-2)  \  qbuf f32 [0,32) from phase 4
    //   [16,32) KVbf bf16     (phase 1-3)  /
    //   [32,48) Qh bf16 head-major (2-4) -> Xbf bf16 (5-6)
    //   [48,64) Kh bf16 head-major, pre-scaled (3-4)
    //   [64,80) Vt bf16 transposed [b,h,d,kv] (3-4)
    //   [80,82) Wbf: WqB,WkB,WvB,WoB contiguous (1-6)
    char* ws = (char*)d_ws;
    unsigned short* Qbf  = (unsigned short*)ws;
    unsigned short* KVbf = (unsigned short*)(ws + ((size_t)16 << 20));
    float*          qbuf = (float*)ws;
    unsigned short* Qh   = (unsigned short*)(ws + ((size_t)32 << 20));
    unsigned short* Xbf  = Qh;
    unsigned short* Kh   = (unsigned short*)(ws + ((size_t)48 << 20));
    unsigned short* Vt   = (unsigned short*)(ws + ((size_t)64 << 20));
    unsigned short* Wbf  = (unsigned short*)(ws + ((size_t)80 << 20));
    unsigned short* WqB  = Wbf;
    unsigned short* WkB  = Wbf + 262144;   // [Wk;Wv] contiguous for merged KV GEMM
    unsigned short* WoB  = Wbf + 786432;

    cvt_act<<<dim3(1024, 2), 256, 0, stream>>>(query, keyv, Qbf, KVbf);
    cvt_w4<<<dim3(64, 4), 256, 0, stream>>>(Wq, Wk, Wv, Wo, Wbf);

    gemm_proj<0><<<dim3(128, 4), 256, 0, stream>>>(Qbf, WqB, bq, nullptr, Qh, nullptr);
    gemm_proj<1><<<dim3(128, 8), 256, 0, stream>>>(KVbf, WkB, bk, bv, Kh, Vt);

    attn_mfma<<<dim3(BATCH * HEADS, 2), 256, 0, stream>>>(Qh, Kh, Vt, qbuf);

    ln0_bf16<<<NROWS, 256, 0, stream>>>(qbuf, ln0w, ln0b, Xbf);

    oproj_ln<<<NROWS / 64, 512, 0, stream>>>(Xbf, WoB, bo, ln1w, ln1b, out);
}

// Round 6
// 168.001 us; speedup vs baseline: 9.9816x; 1.0220x over previous
//
#include <hip/hip_runtime.h>

#define SIZE_D 512
#define HEADS  8
#define HDIM   64
#define BATCH  32
#define SEQ    512
#define SCALE_F 0.125f   // 1/sqrt(64)
#define NROWS  (BATCH * SEQ)   // 16384

typedef __attribute__((ext_vector_type(8))) short bf16x8;
typedef __attribute__((ext_vector_type(4))) float f32x4;
typedef __attribute__((ext_vector_type(4))) unsigned int u32x4;

__device__ __forceinline__ unsigned short f2bf(float f) {
    union { float f; unsigned int u; } c{f};
    unsigned int x = c.u;
    x += 0x7fffu + ((x >> 16) & 1u);   // RNE
    return (unsigned short)(x >> 16);
}
__device__ __forceinline__ float bf2f(unsigned short u) {
    union { unsigned int i; float f; } c;
    c.i = (unsigned int)u << 16;
    return c.f;
}
__device__ __forceinline__ void gload_lds16(const unsigned short* g, unsigned short* l) {
    __builtin_amdgcn_global_load_lds(
        (const __attribute__((address_space(1))) unsigned int*)g,
        (__attribute__((address_space(3))) unsigned int*)l, 16, 0, 0);
}

// ---------------------------------------------------------------------------
// activations f32 -> bf16
// ---------------------------------------------------------------------------
__global__ __launch_bounds__(256) void cvt_act(const float* __restrict__ q,
                                               const float* __restrict__ kv,
                                               unsigned short* __restrict__ dq,
                                               unsigned short* __restrict__ dkv) {
    const float* s = blockIdx.y ? kv : q;
    unsigned short* d = blockIdx.y ? dkv : dq;
    const int n = NROWS * SIZE_D;
    const int stride = gridDim.x * blockDim.x * 4;
    for (int i = (blockIdx.x * blockDim.x + threadIdx.x) * 4; i < n; i += stride) {
        const float4 v = *reinterpret_cast<const float4*>(s + i);
        ushort4 o;
        o.x = f2bf(v.x); o.y = f2bf(v.y); o.z = f2bf(v.z); o.w = f2bf(v.w);
        *reinterpret_cast<ushort4*>(d + i) = o;
    }
}

// 4 weight matrices (512x512) -> contiguous bf16 [Wq;Wk;Wv;Wo]
__global__ __launch_bounds__(256) void cvt_w4(const float* __restrict__ w0,
                                              const float* __restrict__ w1,
                                              const float* __restrict__ w2,
                                              const float* __restrict__ w3,
                                              unsigned short* __restrict__ d) {
    const float* srcs[4] = {w0, w1, w2, w3};
    const float* s = srcs[blockIdx.y];
    unsigned short* dst = d + (size_t)blockIdx.y * (SIZE_D * SIZE_D);
    const int n = SIZE_D * SIZE_D;
    const int stride = gridDim.x * blockDim.x * 4;
    for (int i = (blockIdx.x * blockDim.x + threadIdx.x) * 4; i < n; i += stride) {
        const float4 v = *reinterpret_cast<const float4*>(s + i);
        ushort4 o;
        o.x = f2bf(v.x); o.y = f2bf(v.y); o.z = f2bf(v.z); o.w = f2bf(v.w);
        *reinterpret_cast<ushort4*>(dst + i) = o;
    }
}

// ---------------------------------------------------------------------------
// Merged projection GEMM: grid (128, 12).
//   y 0..3 : Q  = Qbf @ Wq^T + bq -> Qh head-major bf16
//   y 4..7 : K  = KVbf @ Wk^T + bk -> Kh head-major bf16, pre-scaled by 1/8
//   y 8..11: V  = KVbf @ Wv^T + bv -> Vt transposed [b,h,d,kv] bf16
// Wall rows = [Wq;Wk;Wv] contiguous (1536x512 bf16).
// 128x128 tile, BK=64, 4 waves, global_load_lds w/ pre-swizzled source.
// ---------------------------------------------------------------------------
__global__ __launch_bounds__(256, 2) void gemm_proj3(const unsigned short* __restrict__ Qbf,
                                                     const unsigned short* __restrict__ KVbf,
                                                     const unsigned short* __restrict__ Wall,
                                                     const float* __restrict__ bq,
                                                     const float* __restrict__ bk,
                                                     const float* __restrict__ bv,
                                                     unsigned short* __restrict__ Qh,
                                                     unsigned short* __restrict__ Kh,
                                                     unsigned short* __restrict__ Vt) {
    __shared__ __align__(16) unsigned short Ad[2][128 * 64];
    __shared__ __align__(16) unsigned short Bd[2][128 * 64];

    const int tid  = threadIdx.x;
    const int wv   = tid >> 6;
    const int lane = tid & 63;
    const int y    = blockIdx.y;
    const int bm   = blockIdx.x * 128;
    const int bn   = y * 128;                    // row into Wall
    const int wr   = wv >> 1;
    const int wc   = wv & 1;

    const unsigned short* A = (y < 4) ? Qbf : KVbf;

    auto stage = [&](int buf, int t) {
        const int k0 = t * 64;
#pragma unroll
        for (int i = 0; i < 4; ++i) {
            const int o     = (wv * 32 + i * 8) * 128 + lane * 16;
            const int row   = o >> 7;
            const int inrow = (o & 127) ^ ((row & 7) << 4);
            const int col   = inrow >> 1;
            gload_lds16(A + (size_t)(bm + row) * SIZE_D + k0 + col, &Ad[buf][o >> 1]);
            gload_lds16(Wall + (size_t)(bn + row) * SIZE_D + k0 + col, &Bd[buf][o >> 1]);
        }
    };

    f32x4 acc[4][4];
#pragma unroll
    for (int mt = 0; mt < 4; ++mt)
#pragma unroll
        for (int nt = 0; nt < 4; ++nt) acc[mt][nt] = (f32x4){0.f, 0.f, 0.f, 0.f};

    stage(0, 0);
    __syncthreads();
    int cur = 0;

    for (int t = 0; t < 8; ++t) {
        if (t < 7) stage(cur ^ 1, t + 1);

        bf16x8 af[2][4], bfr[2][4];
#pragma unroll
        for (int kc = 0; kc < 2; ++kc) {
#pragma unroll
            for (int mt = 0; mt < 4; ++mt) {
                const int r = wr * 64 + mt * 16 + (lane & 15);
                int byte = r * 128 + kc * 64 + (lane >> 4) * 16;
                byte ^= (r & 7) << 4;
                af[kc][mt] = *reinterpret_cast<const bf16x8*>(
                    reinterpret_cast<const char*>(&Ad[cur][0]) + byte);
            }
#pragma unroll
            for (int nt = 0; nt < 4; ++nt) {
                const int r = wc * 64 + nt * 16 + (lane & 15);
                int byte = r * 128 + kc * 64 + (lane >> 4) * 16;
                byte ^= (r & 7) << 4;
                bfr[kc][nt] = *reinterpret_cast<const bf16x8*>(
                    reinterpret_cast<const char*>(&Bd[cur][0]) + byte);
            }
        }
#pragma unroll
        for (int kc = 0; kc < 2; ++kc)
#pragma unroll
            for (int mt = 0; mt < 4; ++mt)
#pragma unroll
                for (int nt = 0; nt < 4; ++nt)
                    acc[mt][nt] = __builtin_amdgcn_mfma_f32_16x16x32_bf16(
                        af[kc][mt], bfr[kc][nt], acc[mt][nt], 0, 0, 0);

        __syncthreads();
        cur ^= 1;
    }

    if (y < 8) {
        // Q or K path: head-major bf16 (K pre-scaled)
        const float* bias = (y < 4) ? bq : bk;
        unsigned short* D = (y < 4) ? Qh : Kh;
        const int coff = (y < 4) ? 0 : 512;
#pragma unroll
        for (int nt = 0; nt < 4; ++nt) {
            const int colL = bn - coff + wc * 64 + nt * 16 + (lane & 15);
            const float bc = bias[colL];
            const int h = colL >> 6, dd = colL & 63;
#pragma unroll
            for (int mt = 0; mt < 4; ++mt) {
                const int row0 = bm + wr * 64 + mt * 16 + (lane >> 4) * 4;
#pragma unroll
                for (int r = 0; r < 4; ++r) {
                    const int row = row0 + r;
                    const int b_ = row >> 9, l = row & 511;
                    float z = acc[mt][nt][r] + bc;
                    if (y >= 4) z *= SCALE_F;
                    D[(((size_t)b_ * HEADS + h) * SEQ + l) * HDIM + dd] = f2bf(z);
                }
            }
        }
    } else {
        // V path: transposed Vt[b,h,d,kv], 4 consecutive kv packed per 8B store
#pragma unroll
        for (int nt = 0; nt < 4; ++nt) {
            const int c2 = bn - 1024 + wc * 64 + nt * 16 + (lane & 15);
            const float bc = bv[c2];
            const int hV = c2 >> 6, dV = c2 & 63;
#pragma unroll
            for (int mt = 0; mt < 4; ++mt) {
                const int row0 = bm + wr * 64 + mt * 16 + (lane >> 4) * 4;
                const int b_ = row0 >> 9, kv = row0 & 511;
                ushort4 pk;
                pk.x = f2bf(acc[mt][nt][0] + bc);
                pk.y = f2bf(acc[mt][nt][1] + bc);
                pk.z = f2bf(acc[mt][nt][2] + bc);
                pk.w = f2bf(acc[mt][nt][3] + bc);
                *reinterpret_cast<ushort4*>(
                    &Vt[(((size_t)b_ * HEADS + hV) * HDIM + dV) * SEQ + kv]) = pk;
            }
        }
    }
}

// ---------------------------------------------------------------------------
// MFMA attention. Block = (bh, half): 256 thr = 4 waves x 64 q-rows.
// K,Vt tiles double-buffered in LDS via global_load_lds (pre-swizzled src).
// LDS = 16+16+32 = 64KB -> 2 blocks/CU.
// ---------------------------------------------------------------------------
__global__ __launch_bounds__(256, 2) void attn_mfma(const unsigned short* __restrict__ Qh,
                                                    const unsigned short* __restrict__ Kh,
                                                    const unsigned short* __restrict__ Vt,
                                                    float* __restrict__ outq) {
    __shared__ __align__(16) unsigned short Kt[2][64 * 64];   // [kv][d] swizzled
    __shared__ __align__(16) unsigned short Vs[2][64 * 64];   // [d][kv] swizzled
    __shared__ __align__(16) unsigned short WL[4][64 * 64];   // per-wave P[q][k]

    const int tid  = threadIdx.x;
    const int wv   = tid >> 6;
    const int lane = tid & 63;
    const int bh   = blockIdx.x;
    const int half = blockIdx.y;
    const int b    = bh >> 3;
    const int h    = bh & 7;

    const unsigned short* Qb = Qh + (size_t)bh * (SEQ * HDIM);
    const unsigned short* Kb = Kh + (size_t)bh * (SEQ * HDIM);
    const unsigned short* Vb = Vt + (size_t)bh * (HDIM * SEQ);

    const int m0 = half * 256 + wv * 64;

    auto stageKV = [&](int buf, int t) {
        const int kv0 = t * 64;
#pragma unroll
        for (int i = 0; i < 2; ++i) {
            const int o   = i * 4096 + tid * 16;
            const int row = o >> 7;
            const int in  = (o & 127) ^ ((row & 7) << 4);
            gload_lds16(Kb + (size_t)(kv0 + row) * HDIM + (in >> 1), &Kt[buf][o >> 1]);
            gload_lds16(Vb + (size_t)row * SEQ + kv0 + (in >> 1), &Vs[buf][o >> 1]);
        }
    };

    // Q fragments (A-layout: row=lane&15, k=8*(lane>>4)+j)
    bf16x8 qf[4][2];
#pragma unroll
    for (int mt = 0; mt < 4; ++mt)
#pragma unroll
        for (int kc = 0; kc < 2; ++kc) {
            const int m = m0 + mt * 16 + (lane & 15);
            union { u32x4 u; bf16x8 v; } cv;
            cv.u = *reinterpret_cast<const u32x4*>(
                Qb + (size_t)m * HDIM + kc * 32 + (lane >> 4) * 8);
            qf[mt][kc] = cv.v;
        }

    unsigned short* myW = &WL[wv][0];
    f32x4 oacc[4][4];
    float esum[4] = {0.f, 0.f, 0.f, 0.f};
#pragma unroll
    for (int mt = 0; mt < 4; ++mt)
#pragma unroll
        for (int x = 0; x < 4; ++x) oacc[mt][x] = (f32x4){0.f, 0.f, 0.f, 0.f};

    stageKV(0, 0);
    __syncthreads();
    int cur = 0;

    for (int t = 0; t < 8; ++t) {
        if (t < 7) stageKV(cur ^ 1, t + 1);

        f32x4 sacc[4][4];   // [nt=k-tile][mt=q-tile]
#pragma unroll
        for (int nt = 0; nt < 4; ++nt)
#pragma unroll
            for (int mt = 0; mt < 4; ++mt) sacc[nt][mt] = (f32x4){0.f, 0.f, 0.f, 0.f};

#pragma unroll
        for (int kc = 0; kc < 2; ++kc) {
            bf16x8 kf[4];
#pragma unroll
            for (int nt = 0; nt < 4; ++nt) {
                const int kvl = nt * 16 + (lane & 15);
                int byte = kvl * 128 + kc * 64 + (lane >> 4) * 16;
                byte ^= (kvl & 7) << 4;
                kf[nt] = *reinterpret_cast<const bf16x8*>(
                    reinterpret_cast<const char*>(&Kt[cur][0]) + byte);
            }
#pragma unroll
            for (int nt = 0; nt < 4; ++nt)
#pragma unroll
                for (int mt = 0; mt < 4; ++mt)
                    sacc[nt][mt] = __builtin_amdgcn_mfma_f32_16x16x32_bf16(
                        kf[nt], qf[mt][kc], sacc[nt][mt], 0, 0, 0);
        }

        // transform: w = tanh(s)*e^u, u = sqrt(s^2+0.01); e^u = e^|s| * poly(u-|s|)
#pragma unroll
        for (int nt = 0; nt < 4; ++nt)
#pragma unroll
            for (int mt = 0; mt < 4; ++mt) {
                float w[4];
#pragma unroll
                for (int r = 0; r < 4; ++r) {
                    const float s  = sacc[nt][mt][r];
                    const float a  = fminf(fabsf(s), 30.0f);
                    const float tt = __expf(a);
                    const float t2 = tt * tt;
                    const float u  = __builtin_amdgcn_sqrtf(fmaf(s, s, 0.01f));
                    const float dl = u - a;
                    const float ed = fmaf(dl, fmaf(dl, fmaf(dl, 0.16666667f, 0.5f), 1.0f), 1.0f);
                    const float eu = tt * ed;
                    esum[mt] += eu;
                    const float th = (t2 - 1.0f) * __builtin_amdgcn_rcpf(t2 + 1.0f);
                    w[r] = __builtin_copysignf(th * eu, s);
                }
                uint2 pk;   // truncating bf16 pack
                pk.x = (__float_as_uint(w[1]) & 0xffff0000u) | (__float_as_uint(w[0]) >> 16);
                pk.y = (__float_as_uint(w[3]) & 0xffff0000u) | (__float_as_uint(w[2]) >> 16);
                int byte = (mt * 16 + (lane & 15)) * 128 + nt * 32 + (lane >> 4) * 8;
                byte ^= (lane & 7) << 4;
                *reinterpret_cast<uint2*>(reinterpret_cast<char*>(myW) + byte) = pk;
            }

        // PV: O += P * V
#pragma unroll
        for (int kc2 = 0; kc2 < 2; ++kc2) {
            bf16x8 wf[4], vf[4];
#pragma unroll
            for (int mt = 0; mt < 4; ++mt) {
                const int row = mt * 16 + (lane & 15);
                int byte = row * 128 + kc2 * 64 + (lane >> 4) * 16;
                byte ^= (row & 7) << 4;
                wf[mt] = *reinterpret_cast<const bf16x8*>(
                    reinterpret_cast<const char*>(myW) + byte);
            }
#pragma unroll
            for (int dt = 0; dt < 4; ++dt) {
                const int d = dt * 16 + (lane & 15);
                int byte = d * 128 + kc2 * 64 + (lane >> 4) * 16;
                byte ^= (d & 7) << 4;
                vf[dt] = *reinterpret_cast<const bf16x8*>(
                    reinterpret_cast<const char*>(&Vs[cur][0]) + byte);
            }
#pragma unroll
            for (int mt = 0; mt < 4; ++mt)
#pragma unroll
                for (int dt = 0; dt < 4; ++dt)
                    oacc[mt][dt] = __builtin_amdgcn_mfma_f32_16x16x32_bf16(
                        wf[mt], vf[dt], oacc[mt][dt], 0, 0, 0);
        }

        __syncthreads();
        cur ^= 1;
    }

    // epilogue
    float rden[4];
#pragma unroll
    for (int mt = 0; mt < 4; ++mt) {
        float e = esum[mt];
        e += __shfl_xor(e, 16);
        e += __shfl_xor(e, 32);
        rden[mt] = __builtin_amdgcn_rcpf(e);
    }
    float rr_[4][4];
#pragma unroll
    for (int mt = 0; mt < 4; ++mt)
#pragma unroll
        for (int r = 0; r < 4; ++r)
            rr_[mt][r] = __shfl(rden[mt], (lane >> 4) * 4 + r);

#pragma unroll
    for (int mt = 0; mt < 4; ++mt)
#pragma unroll
        for (int dt = 0; dt < 4; ++dt)
#pragma unroll
            for (int r = 0; r < 4; ++r) {
                const int m = m0 + mt * 16 + (lane >> 4) * 4 + r;
                const int d = dt * 16 + (lane & 15);
                const float qv = bf2f(Qb[(size_t)m * HDIM + d]);
                outq[((size_t)b * SEQ + m) * SIZE_D + h * HDIM + d] =
                    qv + oacc[mt][dt][r] * rr_[mt][r];
            }
}

// ---------------------------------------------------------------------------
// LN0: f32 in -> bf16 out (serves as GEMM-A and residual R)
// ---------------------------------------------------------------------------
__global__ __launch_bounds__(256) void ln0_bf16(const float* __restrict__ in,
                                                const float* __restrict__ w,
                                                const float* __restrict__ b,
                                                unsigned short* __restrict__ outb) {
    const int row = blockIdx.x;
    const int tid = threadIdx.x;
    const float2 x = *reinterpret_cast<const float2*>(&in[(size_t)row * SIZE_D + tid * 2]);

    float s  = x.x + x.y;
    float sq = x.x * x.x + x.y * x.y;
#pragma unroll
    for (int off = 32; off > 0; off >>= 1) {
        s  += __shfl_xor(s, off);
        sq += __shfl_xor(sq, off);
    }
    __shared__ float rs[4], rq[4];
    const int wv = tid >> 6;
    if ((tid & 63) == 0) { rs[wv] = s; rq[wv] = sq; }
    __syncthreads();
    s  = rs[0] + rs[1] + rs[2] + rs[3];
    sq = rq[0] + rq[1] + rq[2] + rq[3];

    const float mu  = s * (1.0f / SIZE_D);
    const float var = sq * (1.0f / SIZE_D) - mu * mu;
    const float rr  = rsqrtf(var + 1e-5f);

    const float2 wv2 = *reinterpret_cast<const float2*>(&w[tid * 2]);
    const float2 bv2 = *reinterpret_cast<const float2*>(&b[tid * 2]);
    ushort2 ob;
    ob.x = f2bf((x.x - mu) * rr * wv2.x + bv2.x);
    ob.y = f2bf((x.y - mu) * rr * wv2.y + bv2.y);
    *reinterpret_cast<ushort2*>(&outb[(size_t)row * SIZE_D + tid * 2]) = ob;
}

// ---------------------------------------------------------------------------
// Fused out-proj + ReLU + residual + LN1 -> d_out.
// 64 rows x 512 cols per block; BK=32 -> LDS 76.5KB -> 2 blocks/CU.
// 64B-row swizzle: byte ^= ((row>>1)&3)<<4 (2-way max, free).
// ---------------------------------------------------------------------------
__global__ __launch_bounds__(512, 2) void oproj_ln(const unsigned short* __restrict__ X,
                                                   const unsigned short* __restrict__ W,
                                                   const float* __restrict__ bo,
                                                   const float* __restrict__ g1,
                                                   const float* __restrict__ b1,
                                                   float* __restrict__ out) {
    __shared__ __align__(16) unsigned short Ad[2][64 * 32];    // 8KB
    __shared__ __align__(16) unsigned short Bd[2][512 * 32];   // 64KB
    __shared__ float red[64][8][2];                            // 4KB
    __shared__ float stat[64][2];

    const int tid  = threadIdx.x;
    const int wv   = tid >> 6;
    const int lane = tid & 63;
    const int bm   = blockIdx.x * 64;

    auto stage = [&](int buf, int t) {
        const int k0 = t * 32;
        if (tid < 256) {
            const int o   = tid * 16;
            const int row = o >> 6;
            const int in  = (o & 63) ^ (((row >> 1) & 3) << 4);
            gload_lds16(X + (size_t)(bm + row) * SIZE_D + k0 + (in >> 1), &Ad[buf][o >> 1]);
        }
#pragma unroll
        for (int i = 0; i < 4; ++i) {
            const int o   = i * 8192 + tid * 16;
            const int row = o >> 6;
            const int in  = (o & 63) ^ (((row >> 1) & 3) << 4);
            gload_lds16(W + (size_t)row * SIZE_D + k0 + (in >> 1), &Bd[buf][o >> 1]);
        }
    };

    f32x4 acc[4][4];
#pragma unroll
    for (int mt = 0; mt < 4; ++mt)
#pragma unroll
        for (int nt = 0; nt < 4; ++nt) acc[mt][nt] = (f32x4){0.f, 0.f, 0.f, 0.f};

    stage(0, 0);
    __syncthreads();
    int cur = 0;

    for (int t = 0; t < 16; ++t) {
        if (t < 15) stage(cur ^ 1, t + 1);

        bf16x8 af[4], bfr[4];
#pragma unroll
        for (int mt = 0; mt < 4; ++mt) {
            const int r = mt * 16 + (lane & 15);
            int byte = r * 64 + (lane >> 4) * 16;
            byte ^= ((r >> 1) & 3) << 4;
            af[mt] = *reinterpret_cast<const bf16x8*>(
                reinterpret_cast<const char*>(&Ad[cur][0]) + byte);
        }
#pragma unroll
        for (int nt = 0; nt < 4; ++nt) {
            const int r = wv * 64 + nt * 16 + (lane & 15);
            int byte = r * 64 + (lane >> 4) * 16;
            byte ^= ((r >> 1) & 3) << 4;
            bfr[nt] = *reinterpret_cast<const bf16x8*>(
                reinterpret_cast<const char*>(&Bd[cur][0]) + byte);
        }
#pragma unroll
        for (int mt = 0; mt < 4; ++mt)
#pragma unroll
            for (int nt = 0; nt < 4; ++nt)
                acc[mt][nt] = __builtin_amdgcn_mfma_f32_16x16x32_bf16(
                    af[mt], bfr[nt], acc[mt][nt], 0, 0, 0);

        __syncthreads();
        cur ^= 1;
    }

    // epilogue pass 1: y = R + relu(z + bo)
#pragma unroll
    for (int nt = 0; nt < 4; ++nt) {
        const int n  = wv * 64 + nt * 16 + (lane & 15);
        const float bc = bo[n];
#pragma unroll
        for (int mt = 0; mt < 4; ++mt) {
            const int row0 = bm + mt * 16 + (lane >> 4) * 4;
#pragma unroll
            for (int r = 0; r < 4; ++r) {
                const float R = bf2f(X[(size_t)(row0 + r) * SIZE_D + n]);
                acc[mt][nt][r] = R + fmaxf(acc[mt][nt][r] + bc, 0.0f);
            }
        }
    }

    // LN1 row stats
    float ps[4][4], pq[4][4];
#pragma unroll
    for (int mt = 0; mt < 4; ++mt)
#pragma unroll
        for (int r = 0; r < 4; ++r) {
            float s = 0.f, q = 0.f;
#pragma unroll
            for (int nt = 0; nt < 4; ++nt) {
                const float v = acc[mt][nt][r];
                s += v; q += v * v;
            }
#pragma unroll
            for (int off = 1; off <= 8; off <<= 1) {
                s += __shfl_xor(s, off);
                q += __shfl_xor(q, off);
            }
            ps[mt][r] = s; pq[mt][r] = q;
        }
    {
        const int mtw = (lane & 15) >> 2, rw = lane & 3;
        const int rowL = mtw * 16 + (lane >> 4) * 4 + rw;
        red[rowL][wv][0] = ps[mtw][rw];
        red[rowL][wv][1] = pq[mtw][rw];
    }
    __syncthreads();
    if (tid < 64) {
        float s = 0.f, q = 0.f;
#pragma unroll
        for (int w8 = 0; w8 < 8; ++w8) { s += red[tid][w8][0]; q += red[tid][w8][1]; }
        const float mu  = s * (1.0f / SIZE_D);
        const float var = q * (1.0f / SIZE_D) - mu * mu;
        stat[tid][0] = mu;
        stat[tid][1] = rsqrtf(var + 1e-5f);
    }
    __syncthreads();

    // normalize + write
#pragma unroll
    for (int nt = 0; nt < 4; ++nt) {
        const int n = wv * 64 + nt * 16 + (lane & 15);
        const float g = g1[n], bb = b1[n];
#pragma unroll
        for (int mt = 0; mt < 4; ++mt) {
#pragma unroll
            for (int r = 0; r < 4; ++r) {
                const int rowL = mt * 16 + (lane >> 4) * 4 + r;
                const float y = (acc[mt][nt][r] - stat[rowL][0]) * stat[rowL][1];
                out[(size_t)(bm + rowL) * SIZE_D + n] = y * g + bb;
            }
        }
    }
}

// ---------------------------------------------------------------------------
extern "C" void kernel_launch(void* const* d_in, const int* in_sizes, int n_in,
                              void* d_out, int out_size, void* d_ws, size_t ws_size,
                              hipStream_t stream) {
    const float* query = (const float*)d_in[0];
    const float* keyv  = (const float*)d_in[1];
    const float* Wq    = (const float*)d_in[2];
    const float* bq    = (const float*)d_in[3];
    const float* Wk    = (const float*)d_in[4];
    const float* bk    = (const float*)d_in[5];
    const float* Wv    = (const float*)d_in[6];
    const float* bv    = (const float*)d_in[7];
    const float* Wo    = (const float*)d_in[8];
    const float* bo    = (const float*)d_in[9];
    const float* ln0w  = (const float*)d_in[10];
    const float* ln0b  = (const float*)d_in[11];
    const float* ln1w  = (const float*)d_in[12];
    const float* ln1b  = (const float*)d_in[13];
    float* out = (float*)d_out;

    // workspace layout:
    //   [ 0,16) Qbf bf16      \  qbuf f32 [0,32) after attention
    //   [16,32) KVbf bf16     /
    //   [32,48) Qh bf16 head-major -> Xbf bf16 after ln0
    //   [48,64) Kh bf16 head-major (pre-scaled)
    //   [64,80) Vt bf16 transposed [b,h,d,kv]
    //   [80,82) Wbf: [Wq;Wk;Wv;Wo] bf16 contiguous
    char* ws = (char*)d_ws;
    unsigned short* Qbf  = (unsigned short*)ws;
    unsigned short* KVbf = (unsigned short*)(ws + ((size_t)16 << 20));
    float*          qbuf = (float*)ws;
    unsigned short* Qh   = (unsigned short*)(ws + ((size_t)32 << 20));
    unsigned short* Xbf  = Qh;
    unsigned short* Kh   = (unsigned short*)(ws + ((size_t)48 << 20));
    unsigned short* Vt   = (unsigned short*)(ws + ((size_t)64 << 20));
    unsigned short* Wbf  = (unsigned short*)(ws + ((size_t)80 << 20));
    unsigned short* WoB  = Wbf + 786432;

    cvt_act<<<dim3(1024, 2), 256, 0, stream>>>(query, keyv, Qbf, KVbf);
    cvt_w4<<<dim3(64, 4), 256, 0, stream>>>(Wq, Wk, Wv, Wo, Wbf);

    gemm_proj3<<<dim3(128, 12), 256, 0, stream>>>(Qbf, KVbf, Wbf, bq, bk, bv, Qh, Kh, Vt);

    attn_mfma<<<dim3(BATCH * HEADS, 2), 256, 0, stream>>>(Qh, Kh, Vt, qbuf);

    ln0_bf16<<<NROWS, 256, 0, stream>>>(qbuf, ln0w, ln0b, Xbf);

    oproj_ln<<<NROWS / 64, 512, 0, stream>>>(Xbf, WoB, bo, ln1w, ln1b, out);
}

// Round 8
// 166.382 us; speedup vs baseline: 10.0787x; 1.0097x over previous
//
#include <hip/hip_runtime.h>

#define SIZE_D 512
#define HEADS  8
#define HDIM   64
#define BATCH  32
#define SEQ    512
#define SCALE_F 0.125f   // 1/sqrt(64)
#define NROWS  (BATCH * SEQ)   // 16384

typedef __attribute__((ext_vector_type(8))) short bf16x8;
typedef __attribute__((ext_vector_type(4))) float f32x4;
typedef __attribute__((ext_vector_type(4))) unsigned int u32x4;

__device__ __forceinline__ unsigned short f2bf(float f) {
    union { float f; unsigned int u; } c{f};
    unsigned int x = c.u;
    x += 0x7fffu + ((x >> 16) & 1u);   // RNE
    return (unsigned short)(x >> 16);
}
__device__ __forceinline__ float bf2f(unsigned short u) {
    union { unsigned int i; float f; } c;
    c.i = (unsigned int)u << 16;
    return c.f;
}
__device__ __forceinline__ void gload_lds16(const unsigned short* g, unsigned short* l) {
    __builtin_amdgcn_global_load_lds(
        (const __attribute__((address_space(1))) unsigned int*)g,
        (__attribute__((address_space(3))) unsigned int*)l, 16, 0, 0);
}

// ---------------------------------------------------------------------------
// activations f32 -> bf16
// ---------------------------------------------------------------------------
__global__ __launch_bounds__(256) void cvt_act(const float* __restrict__ q,
                                               const float* __restrict__ kv,
                                               unsigned short* __restrict__ dq,
                                               unsigned short* __restrict__ dkv) {
    const float* s = blockIdx.y ? kv : q;
    unsigned short* d = blockIdx.y ? dkv : dq;
    const int n = NROWS * SIZE_D;
    const int stride = gridDim.x * blockDim.x * 4;
    for (int i = (blockIdx.x * blockDim.x + threadIdx.x) * 4; i < n; i += stride) {
        const float4 v = *reinterpret_cast<const float4*>(s + i);
        ushort4 o;
        o.x = f2bf(v.x); o.y = f2bf(v.y); o.z = f2bf(v.z); o.w = f2bf(v.w);
        *reinterpret_cast<ushort4*>(d + i) = o;
    }
}

// 4 weight matrices (512x512) -> contiguous bf16 [Wq;Wk;Wv;Wo]
__global__ __launch_bounds__(256) void cvt_w4(const float* __restrict__ w0,
                                              const float* __restrict__ w1,
                                              const float* __restrict__ w2,
                                              const float* __restrict__ w3,
                                              unsigned short* __restrict__ d) {
    const float* srcs[4] = {w0, w1, w2, w3};
    const float* s = srcs[blockIdx.y];
    unsigned short* dst = d + (size_t)blockIdx.y * (SIZE_D * SIZE_D);
    const int n = SIZE_D * SIZE_D;
    const int stride = gridDim.x * blockDim.x * 4;
    for (int i = (blockIdx.x * blockDim.x + threadIdx.x) * 4; i < n; i += stride) {
        const float4 v = *reinterpret_cast<const float4*>(s + i);
        ushort4 o;
        o.x = f2bf(v.x); o.y = f2bf(v.y); o.z = f2bf(v.z); o.w = f2bf(v.w);
        *reinterpret_cast<ushort4*>(dst + i) = o;
    }
}

// ---------------------------------------------------------------------------
// Merged projection GEMM: grid (128, 12).
//   y 0..3 : Q -> Qh head-major bf16; y 4..7 : K -> Kh (pre-scaled);
//   y 8..11: V -> Vt transposed [b,h,d,kv].
// ---------------------------------------------------------------------------
__global__ __launch_bounds__(256, 2) void gemm_proj3(const unsigned short* __restrict__ Qbf,
                                                     const unsigned short* __restrict__ KVbf,
                                                     const unsigned short* __restrict__ Wall,
                                                     const float* __restrict__ bq,
                                                     const float* __restrict__ bk,
                                                     const float* __restrict__ bv,
                                                     unsigned short* __restrict__ Qh,
                                                     unsigned short* __restrict__ Kh,
                                                     unsigned short* __restrict__ Vt) {
    __shared__ __align__(16) unsigned short Ad[2][128 * 64];
    __shared__ __align__(16) unsigned short Bd[2][128 * 64];

    const int tid  = threadIdx.x;
    const int wv   = tid >> 6;
    const int lane = tid & 63;
    const int y    = blockIdx.y;
    const int bm   = blockIdx.x * 128;
    const int bn   = y * 128;
    const int wr   = wv >> 1;
    const int wc   = wv & 1;

    const unsigned short* A = (y < 4) ? Qbf : KVbf;

    auto stage = [&](int buf, int t) {
        const int k0 = t * 64;
#pragma unroll
        for (int i = 0; i < 4; ++i) {
            const int o     = (wv * 32 + i * 8) * 128 + lane * 16;
            const int row   = o >> 7;
            const int inrow = (o & 127) ^ ((row & 7) << 4);
            const int col   = inrow >> 1;
            gload_lds16(A + (size_t)(bm + row) * SIZE_D + k0 + col, &Ad[buf][o >> 1]);
            gload_lds16(Wall + (size_t)(bn + row) * SIZE_D + k0 + col, &Bd[buf][o >> 1]);
        }
    };

    f32x4 acc[4][4];
#pragma unroll
    for (int mt = 0; mt < 4; ++mt)
#pragma unroll
        for (int nt = 0; nt < 4; ++nt) acc[mt][nt] = (f32x4){0.f, 0.f, 0.f, 0.f};

    stage(0, 0);
    __syncthreads();
    int cur = 0;

    for (int t = 0; t < 8; ++t) {
        if (t < 7) stage(cur ^ 1, t + 1);

        bf16x8 af[2][4], bfr[2][4];
#pragma unroll
        for (int kc = 0; kc < 2; ++kc) {
#pragma unroll
            for (int mt = 0; mt < 4; ++mt) {
                const int r = wr * 64 + mt * 16 + (lane & 15);
                int byte = r * 128 + kc * 64 + (lane >> 4) * 16;
                byte ^= (r & 7) << 4;
                af[kc][mt] = *reinterpret_cast<const bf16x8*>(
                    reinterpret_cast<const char*>(&Ad[cur][0]) + byte);
            }
#pragma unroll
            for (int nt = 0; nt < 4; ++nt) {
                const int r = wc * 64 + nt * 16 + (lane & 15);
                int byte = r * 128 + kc * 64 + (lane >> 4) * 16;
                byte ^= (r & 7) << 4;
                bfr[kc][nt] = *reinterpret_cast<const bf16x8*>(
                    reinterpret_cast<const char*>(&Bd[cur][0]) + byte);
            }
        }
#pragma unroll
        for (int kc = 0; kc < 2; ++kc)
#pragma unroll
            for (int mt = 0; mt < 4; ++mt)
#pragma unroll
                for (int nt = 0; nt < 4; ++nt)
                    acc[mt][nt] = __builtin_amdgcn_mfma_f32_16x16x32_bf16(
                        af[kc][mt], bfr[kc][nt], acc[mt][nt], 0, 0, 0);

        __syncthreads();
        cur ^= 1;
    }

    if (y < 8) {
        const float* bias = (y < 4) ? bq : bk;
        unsigned short* D = (y < 4) ? Qh : Kh;
        const int coff = (y < 4) ? 0 : 512;
#pragma unroll
        for (int nt = 0; nt < 4; ++nt) {
            const int colL = bn - coff + wc * 64 + nt * 16 + (lane & 15);
            const float bc = bias[colL];
            const int h = colL >> 6, dd = colL & 63;
#pragma unroll
            for (int mt = 0; mt < 4; ++mt) {
                const int row0 = bm + wr * 64 + mt * 16 + (lane >> 4) * 4;
#pragma unroll
                for (int r = 0; r < 4; ++r) {
                    const int row = row0 + r;
                    const int b_ = row >> 9, l = row & 511;
                    float z = acc[mt][nt][r] + bc;
                    if (y >= 4) z *= SCALE_F;
                    D[(((size_t)b_ * HEADS + h) * SEQ + l) * HDIM + dd] = f2bf(z);
                }
            }
        }
    } else {
#pragma unroll
        for (int nt = 0; nt < 4; ++nt) {
            const int c2 = bn - 1024 + wc * 64 + nt * 16 + (lane & 15);
            const float bc = bv[c2];
            const int hV = c2 >> 6, dV = c2 & 63;
#pragma unroll
            for (int mt = 0; mt < 4; ++mt) {
                const int row0 = bm + wr * 64 + mt * 16 + (lane >> 4) * 4;
                const int b_ = row0 >> 9, kv = row0 & 511;
                ushort4 pk;
                pk.x = f2bf(acc[mt][nt][0] + bc);
                pk.y = f2bf(acc[mt][nt][1] + bc);
                pk.z = f2bf(acc[mt][nt][2] + bc);
                pk.w = f2bf(acc[mt][nt][3] + bc);
                *reinterpret_cast<ushort4*>(
                    &Vt[(((size_t)b_ * HEADS + hV) * HDIM + dV) * SEQ + kv]) = pk;
            }
        }
    }
}

// ---------------------------------------------------------------------------
// MFMA attention — round-6 shell (grid (bh,2), 4 waves x 64 q, LB(256,2),
// same stageKV double-buffer) with in-register P replacing the WL round-trip.
// Swapped QK^T: lane holds P[q=lane&15][kv=16*nt+4*g+r].
// PV k-slot permutation kv(g,j)=16*(2c+(j>>2))+4g+(j&3):
//   A-frag = in-register bf16 pack of held P (zero cross-lane moves);
//   B-frag = two permuted ds_read_b64 of swizzled Vs.
// ---------------------------------------------------------------------------
__global__ __launch_bounds__(256, 2) void attn_mfma(const unsigned short* __restrict__ Qh,
                                                    const unsigned short* __restrict__ Kh,
                                                    const unsigned short* __restrict__ Vt,
                                                    float* __restrict__ outq) {
    __shared__ __align__(16) unsigned short Kt[2][64 * 64];   // [kv][d] swizzled
    __shared__ __align__(16) unsigned short Vs[2][64 * 64];   // [d][kv] swizzled

    const int tid  = threadIdx.x;
    const int wv   = tid >> 6;
    const int lane = tid & 63;
    const int bh   = blockIdx.x;
    const int b    = bh >> 3;
    const int h    = bh & 7;
    const int g    = lane >> 4;

    const unsigned short* Qb = Qh + (size_t)bh * (SEQ * HDIM);
    const unsigned short* Kb = Kh + (size_t)bh * (SEQ * HDIM);
    const unsigned short* Vb = Vt + (size_t)bh * (HDIM * SEQ);

    const int m0 = blockIdx.y * 256 + wv * 64;

    auto stageKV = [&](int buf, int t) {
        const int kv0 = t * 64;
#pragma unroll
        for (int i = 0; i < 2; ++i) {
            const int o   = i * 4096 + tid * 16;
            const int row = o >> 7;
            const int in  = (o & 127) ^ ((row & 7) << 4);
            gload_lds16(Kb + (size_t)(kv0 + row) * HDIM + (in >> 1), &Kt[buf][o >> 1]);
            gload_lds16(Vb + (size_t)row * SEQ + kv0 + (in >> 1), &Vs[buf][o >> 1]);
        }
    };

    // Q fragments (A/B-frag layout: row=lane&15, k=8*g+j)
    bf16x8 qf[4][2];
#pragma unroll
    for (int mt = 0; mt < 4; ++mt)
#pragma unroll
        for (int kc = 0; kc < 2; ++kc) {
            const int m = m0 + mt * 16 + (lane & 15);
            union { u32x4 u; bf16x8 v; } cv;
            cv.u = *reinterpret_cast<const u32x4*>(
                Qb + (size_t)m * HDIM + kc * 32 + g * 8);
            qf[mt][kc] = cv.v;
        }

    f32x4 oacc[4][4];
    float esum[4] = {0.f, 0.f, 0.f, 0.f};
#pragma unroll
    for (int mt = 0; mt < 4; ++mt)
#pragma unroll
        for (int x = 0; x < 4; ++x) oacc[mt][x] = (f32x4){0.f, 0.f, 0.f, 0.f};

    stageKV(0, 0);
    __syncthreads();
    int cur = 0;

    for (int t = 0; t < 8; ++t) {
        if (t < 7) stageKV(cur ^ 1, t + 1);

        // ---- QK^T: sacc[nt][mt]; lane holds q=lane&15, kv=16nt+4g+r ----
        f32x4 sacc[4][4];
#pragma unroll
        for (int nt = 0; nt < 4; ++nt)
#pragma unroll
            for (int mt = 0; mt < 4; ++mt) sacc[nt][mt] = (f32x4){0.f, 0.f, 0.f, 0.f};

#pragma unroll
        for (int kc = 0; kc < 2; ++kc) {
            bf16x8 kf[4];
#pragma unroll
            for (int nt = 0; nt < 4; ++nt) {
                const int kvl = nt * 16 + (lane & 15);
                int byte = kvl * 128 + kc * 64 + g * 16;
                byte ^= (kvl & 7) << 4;
                kf[nt] = *reinterpret_cast<const bf16x8*>(
                    reinterpret_cast<const char*>(&Kt[cur][0]) + byte);
            }
#pragma unroll
            for (int nt = 0; nt < 4; ++nt)
#pragma unroll
                for (int mt = 0; mt < 4; ++mt)
                    sacc[nt][mt] = __builtin_amdgcn_mfma_f32_16x16x32_bf16(
                        kf[nt], qf[mt][kc], sacc[nt][mt], 0, 0, 0);
        }

        // ---- transform in-register -> pa[c][mt] (A-frags for PV) ----
        // k-slot j of pa[c][mt] carries kv = 16*(2c+(j>>2)) + 4g + (j&3)
        bf16x8 pa[2][4];
#pragma unroll
        for (int c = 0; c < 2; ++c)
#pragma unroll
            for (int mt = 0; mt < 4; ++mt) {
                float w[8];
#pragma unroll
                for (int j = 0; j < 8; ++j) {
                    const float s  = sacc[2 * c + (j >> 2)][mt][j & 3];
                    const float a  = fminf(fabsf(s), 30.0f);
                    const float tt = __expf(a);
                    const float t2 = tt * tt;
                    const float u  = __builtin_amdgcn_sqrtf(fmaf(s, s, 0.01f));
                    const float dl = u - a;
                    const float ed = fmaf(dl, fmaf(dl, fmaf(dl, 0.16666667f, 0.5f), 1.0f), 1.0f);
                    const float eu = tt * ed;
                    esum[mt] += eu;
                    const float th = (t2 - 1.0f) * __builtin_amdgcn_rcpf(t2 + 1.0f);
                    w[j] = __builtin_copysignf(th * eu, s);
                }
                union { unsigned int u[4]; bf16x8 v; } pk;
#pragma unroll
                for (int p = 0; p < 4; ++p)
                    pk.u[p] = (__float_as_uint(w[2 * p + 1]) & 0xffff0000u) |
                              (__float_as_uint(w[2 * p]) >> 16);
                pa[c][mt] = pk.v;
            }

        // ---- PV with permuted B-frags from swizzled Vs ----
#pragma unroll
        for (int c = 0; c < 2; ++c) {
            bf16x8 vf[4];
#pragma unroll
            for (int dt = 0; dt < 4; ++dt) {
                const int d = dt * 16 + (lane & 15);
                const int swz = (d & 7) << 4;
                const int rowb = d * 128;
                uint2 lo = *reinterpret_cast<const uint2*>(
                    reinterpret_cast<const char*>(&Vs[cur][0]) +
                    (rowb + (((c * 32 + 4 * g) * 2) ^ swz)));
                uint2 hi = *reinterpret_cast<const uint2*>(
                    reinterpret_cast<const char*>(&Vs[cur][0]) +
                    (rowb + (((c * 32 + 16 + 4 * g) * 2) ^ swz)));
                union { unsigned int u[4]; bf16x8 v; } cvb;
                cvb.u[0] = lo.x; cvb.u[1] = lo.y;
                cvb.u[2] = hi.x; cvb.u[3] = hi.y;
                vf[dt] = cvb.v;
            }
#pragma unroll
            for (int mt = 0; mt < 4; ++mt)
#pragma unroll
                for (int dt = 0; dt < 4; ++dt)
                    oacc[mt][dt] = __builtin_amdgcn_mfma_f32_16x16x32_bf16(
                        pa[c][mt], vf[dt], oacc[mt][dt], 0, 0, 0);
        }

        __syncthreads();
        cur ^= 1;
    }

    // ---- epilogue: reduce esum, redistribute, normalize, residual ----
    float rden[4];
#pragma unroll
    for (int mt = 0; mt < 4; ++mt) {
        float e = esum[mt];
        e += __shfl_xor(e, 16);
        e += __shfl_xor(e, 32);
        rden[mt] = __builtin_amdgcn_rcpf(e);
    }
    float rr_[4][4];
#pragma unroll
    for (int mt = 0; mt < 4; ++mt)
#pragma unroll
        for (int r = 0; r < 4; ++r)
            rr_[mt][r] = __shfl(rden[mt], g * 4 + r);

#pragma unroll
    for (int mt = 0; mt < 4; ++mt)
#pragma unroll
        for (int dt = 0; dt < 4; ++dt)
#pragma unroll
            for (int r = 0; r < 4; ++r) {
                const int m = m0 + mt * 16 + g * 4 + r;
                const int d = dt * 16 + (lane & 15);
                const float qv = bf2f(Qb[(size_t)m * HDIM + d]);
                outq[((size_t)b * SEQ + m) * SIZE_D + h * HDIM + d] =
                    qv + oacc[mt][dt][r] * rr_[mt][r];
            }
}

// ---------------------------------------------------------------------------
// LN0: f32 in -> bf16 out (serves as GEMM-A and residual R)
// ---------------------------------------------------------------------------
__global__ __launch_bounds__(256) void ln0_bf16(const float* __restrict__ in,
                                                const float* __restrict__ w,
                                                const float* __restrict__ b,
                                                unsigned short* __restrict__ outb) {
    const int row = blockIdx.x;
    const int tid = threadIdx.x;
    const float2 x = *reinterpret_cast<const float2*>(&in[(size_t)row * SIZE_D + tid * 2]);

    float s  = x.x + x.y;
    float sq = x.x * x.x + x.y * x.y;
#pragma unroll
    for (int off = 32; off > 0; off >>= 1) {
        s  += __shfl_xor(s, off);
        sq += __shfl_xor(sq, off);
    }
    __shared__ float rs[4], rq[4];
    const int wv = tid >> 6;
    if ((tid & 63) == 0) { rs[wv] = s; rq[wv] = sq; }
    __syncthreads();
    s  = rs[0] + rs[1] + rs[2] + rs[3];
    sq = rq[0] + rq[1] + rq[2] + rq[3];

    const float mu  = s * (1.0f / SIZE_D);
    const float var = sq * (1.0f / SIZE_D) - mu * mu;
    const float rr  = rsqrtf(var + 1e-5f);

    const float2 wv2 = *reinterpret_cast<const float2*>(&w[tid * 2]);
    const float2 bv2 = *reinterpret_cast<const float2*>(&b[tid * 2]);
    ushort2 ob;
    ob.x = f2bf((x.x - mu) * rr * wv2.x + bv2.x);
    ob.y = f2bf((x.y - mu) * rr * wv2.y + bv2.y);
    *reinterpret_cast<ushort2*>(&outb[(size_t)row * SIZE_D + tid * 2]) = ob;
}

// ---------------------------------------------------------------------------
// Fused out-proj + ReLU + residual + LN1 -> d_out. BK=32, 2 blocks/CU.
// ---------------------------------------------------------------------------
__global__ __launch_bounds__(512, 2) void oproj_ln(const unsigned short* __restrict__ X,
                                                   const unsigned short* __restrict__ W,
                                                   const float* __restrict__ bo,
                                                   const float* __restrict__ g1,
                                                   const float* __restrict__ b1,
                                                   float* __restrict__ out) {
    __shared__ __align__(16) unsigned short Ad[2][64 * 32];
    __shared__ __align__(16) unsigned short Bd[2][512 * 32];
    __shared__ float red[64][8][2];
    __shared__ float stat[64][2];

    const int tid  = threadIdx.x;
    const int wv   = tid >> 6;
    const int lane = tid & 63;
    const int bm   = blockIdx.x * 64;

    auto stage = [&](int buf, int t) {
        const int k0 = t * 32;
        if (tid < 256) {
            const int o   = tid * 16;
            const int row = o >> 6;
            const int in  = (o & 63) ^ (((row >> 1) & 3) << 4);
            gload_lds16(X + (size_t)(bm + row) * SIZE_D + k0 + (in >> 1), &Ad[buf][o >> 1]);
        }
#pragma unroll
        for (int i = 0; i < 4; ++i) {
            const int o   = i * 8192 + tid * 16;
            const int row = o >> 6;
            const int in  = (o & 63) ^ (((row >> 1) & 3) << 4);
            gload_lds16(W + (size_t)row * SIZE_D + k0 + (in >> 1), &Bd[buf][o >> 1]);
        }
    };

    f32x4 acc[4][4];
#pragma unroll
    for (int mt = 0; mt < 4; ++mt)
#pragma unroll
        for (int nt = 0; nt < 4; ++nt) acc[mt][nt] = (f32x4){0.f, 0.f, 0.f, 0.f};

    stage(0, 0);
    __syncthreads();
    int cur = 0;

    for (int t = 0; t < 16; ++t) {
        if (t < 15) stage(cur ^ 1, t + 1);

        bf16x8 af[4], bfr[4];
#pragma unroll
        for (int mt = 0; mt < 4; ++mt) {
            const int r = mt * 16 + (lane & 15);
            int byte = r * 64 + (lane >> 4) * 16;
            byte ^= ((r >> 1) & 3) << 4;
            af[mt] = *reinterpret_cast<const bf16x8*>(
                reinterpret_cast<const char*>(&Ad[cur][0]) + byte);
        }
#pragma unroll
        for (int nt = 0; nt < 4; ++nt) {
            const int r = wv * 64 + nt * 16 + (lane & 15);
            int byte = r * 64 + (lane >> 4) * 16;
            byte ^= ((r >> 1) & 3) << 4;
            bfr[nt] = *reinterpret_cast<const bf16x8*>(
                reinterpret_cast<const char*>(&Bd[cur][0]) + byte);
        }
#pragma unroll
        for (int mt = 0; mt < 4; ++mt)
#pragma unroll
            for (int nt = 0; nt < 4; ++nt)
                acc[mt][nt] = __builtin_amdgcn_mfma_f32_16x16x32_bf16(
                    af[mt], bfr[nt], acc[mt][nt], 0, 0, 0);

        __syncthreads();
        cur ^= 1;
    }

#pragma unroll
    for (int nt = 0; nt < 4; ++nt) {
        const int n  = wv * 64 + nt * 16 + (lane & 15);
        const float bc = bo[n];
#pragma unroll
        for (int mt = 0; mt < 4; ++mt) {
            const int row0 = bm + mt * 16 + (lane >> 4) * 4;
#pragma unroll
            for (int r = 0; r < 4; ++r) {
                const float R = bf2f(X[(size_t)(row0 + r) * SIZE_D + n]);
                acc[mt][nt][r] = R + fmaxf(acc[mt][nt][r] + bc, 0.0f);
            }
        }
    }

    float ps[4][4], pq[4][4];
#pragma unroll
    for (int mt = 0; mt < 4; ++mt)
#pragma unroll
        for (int r = 0; r < 4; ++r) {
            float s = 0.f, q = 0.f;
#pragma unroll
            for (int nt = 0; nt < 4; ++nt) {
                const float v = acc[mt][nt][r];
                s += v; q += v * v;
            }
#pragma unroll
            for (int off = 1; off <= 8; off <<= 1) {
                s += __shfl_xor(s, off);
                q += __shfl_xor(q, off);
            }
            ps[mt][r] = s; pq[mt][r] = q;
        }
    {
        const int mtw = (lane & 15) >> 2, rw = lane & 3;
        const int rowL = mtw * 16 + (lane >> 4) * 4 + rw;
        red[rowL][wv][0] = ps[mtw][rw];
        red[rowL][wv][1] = pq[mtw][rw];
    }
    __syncthreads();
    if (tid < 64) {
        float s = 0.f, q = 0.f;
#pragma unroll
        for (int w8 = 0; w8 < 8; ++w8) { s += red[tid][w8][0]; q += red[tid][w8][1]; }
        const float mu  = s * (1.0f / SIZE_D);
        const float var = q * (1.0f / SIZE_D) - mu * mu;
        stat[tid][0] = mu;
        stat[tid][1] = rsqrtf(var + 1e-5f);
    }
    __syncthreads();

#pragma unroll
    for (int nt = 0; nt < 4; ++nt) {
        const int n = wv * 64 + nt * 16 + (lane & 15);
        const float g = g1[n], bb = b1[n];
#pragma unroll
        for (int mt = 0; mt < 4; ++mt) {
#pragma unroll
            for (int r = 0; r < 4; ++r) {
                const int rowL = mt * 16 + (lane >> 4) * 4 + r;
                const float y = (acc[mt][nt][r] - stat[rowL][0]) * stat[rowL][1];
                out[(size_t)(bm + rowL) * SIZE_D + n] = y * g + bb;
            }
        }
    }
}

// ---------------------------------------------------------------------------
extern "C" void kernel_launch(void* const* d_in, const int* in_sizes, int n_in,
                              void* d_out, int out_size, void* d_ws, size_t ws_size,
                              hipStream_t stream) {
    const float* query = (const float*)d_in[0];
    const float* keyv  = (const float*)d_in[1];
    const float* Wq    = (const float*)d_in[2];
    const float* bq    = (const float*)d_in[3];
    const float* Wk    = (const float*)d_in[4];
    const float* bk    = (const float*)d_in[5];
    const float* Wv    = (const float*)d_in[6];
    const float* bv    = (const float*)d_in[7];
    const float* Wo    = (const float*)d_in[8];
    const float* bo    = (const float*)d_in[9];
    const float* ln0w  = (const float*)d_in[10];
    const float* ln0b  = (const float*)d_in[11];
    const float* ln1w  = (const float*)d_in[12];
    const float* ln1b  = (const float*)d_in[13];
    float* out = (float*)d_out;

    char* ws = (char*)d_ws;
    unsigned short* Qbf  = (unsigned short*)ws;
    unsigned short* KVbf = (unsigned short*)(ws + ((size_t)16 << 20));
    float*          qbuf = (float*)ws;
    unsigned short* Qh   = (unsigned short*)(ws + ((size_t)32 << 20));
    unsigned short* Xbf  = Qh;
    unsigned short* Kh   = (unsigned short*)(ws + ((size_t)48 << 20));
    unsigned short* Vt   = (unsigned short*)(ws + ((size_t)64 << 20));
    unsigned short* Wbf  = (unsigned short*)(ws + ((size_t)80 << 20));
    unsigned short* WoB  = Wbf + 786432;

    cvt_act<<<dim3(1024, 2), 256, 0, stream>>>(query, keyv, Qbf, KVbf);
    cvt_w4<<<dim3(64, 4), 256, 0, stream>>>(Wq, Wk, Wv, Wo, Wbf);

    gemm_proj3<<<dim3(128, 12), 256, 0, stream>>>(Qbf, KVbf, Wbf, bq, bk, bv, Qh, Kh, Vt);

    attn_mfma<<<dim3(BATCH * HEADS, 2), 256, 0, stream>>>(Qh, Kh, Vt, qbuf);

    ln0_bf16<<<NROWS, 256, 0, stream>>>(qbuf, ln0w, ln0b, Xbf);

    oproj_ln<<<NROWS / 64, 512, 0, stream>>>(Xbf, WoB, bo, ln1w, ln1b, out);
}